// Round 5
// baseline (6593.187 us; speedup 1.0000x reference)
//
#include <hip/hip_runtime.h>
#include <math.h>

#define BATCH 2
#define SEQ 2048
#define DM 2048
#define NH 16
#define NG 4
#define DH 128
#define HDIM 5632
#define MROWS (BATCH * SEQ)
#define KVD (NG * DH) /* 512 */

typedef __attribute__((ext_vector_type(8))) short short8;
typedef __attribute__((ext_vector_type(4))) float f32x4;

__device__ __forceinline__ unsigned short f2bf(float x) {
  unsigned int u = __float_as_uint(x);
  u += 0x7FFFu + ((u >> 16) & 1u);  // round-to-nearest-even
  return (unsigned short)(u >> 16);
}
__device__ __forceinline__ float bf2f(unsigned short h) {
  return __uint_as_float(((unsigned int)h) << 16);
}

// ---------------------------------------------------------------------------
// RMSNorm: one block (256 threads) per row of 2048 floats
// ---------------------------------------------------------------------------
__global__ __launch_bounds__(256) void rmsnorm_kernel(
    const float* __restrict__ x, const float* __restrict__ g,
    float* __restrict__ out) {
  int row = blockIdx.x;
  const float4* xr = (const float4*)(x + (size_t)row * DM);
  float4* orow = (float4*)(out + (size_t)row * DM);
  const float4* g4 = (const float4*)g;
  int t = threadIdx.x;
  float4 a = xr[t];
  float4 b = xr[t + 256];
  float ss = a.x * a.x + a.y * a.y + a.z * a.z + a.w * a.w +
             b.x * b.x + b.y * b.y + b.z * b.z + b.w * b.w;
#pragma unroll
  for (int off = 32; off > 0; off >>= 1) ss += __shfl_xor(ss, off);
  __shared__ float red[4];
  if ((t & 63) == 0) red[t >> 6] = ss;
  __syncthreads();
  float tot = red[0] + red[1] + red[2] + red[3];
  float inv = rsqrtf(tot * (1.0f / DM) + 1e-6f);
  float4 ga = g4[t], gb = g4[t + 256];
  float4 oa, ob;
  oa.x = a.x * inv * ga.x; oa.y = a.y * inv * ga.y;
  oa.z = a.z * inv * ga.z; oa.w = a.w * inv * ga.w;
  ob.x = b.x * inv * gb.x; ob.y = b.y * inv * gb.y;
  ob.z = b.z * inv * gb.z; ob.w = b.w * inv * gb.w;
  orow[t] = oa;
  orow[t + 256] = ob;
}

// ---------------------------------------------------------------------------
// bf16x3 split-precision MFMA GEMM: C[M,N] = A[M,K] @ W[K,N] + bias [+ epi]
//   EPI 0: +bias
//   EPI 1: +bias + aux (residual add)
//   EPI 2: (acc+bias) * silu(aux)   [SwiGLU fusion; aux = u buffer]
// 128x128 tile, BK=32, 256 threads = 4 waves (2x2), each wave 64x64 (4x4
// fragments of mfma_f32_16x16x32_bf16). A,W fp32 in global; hi/lo bf16
// planes built during reg-staging (T14 issue-early: next tile's global
// loads are issued right after the "tile ready" barrier so HBM latency
// hides under ds_read+MFMA). LDS rows padded to 40 ushorts (80 B).
// ---------------------------------------------------------------------------
template <int EPI>
__global__ __launch_bounds__(256) void gemm_bf16x3(
    const float* __restrict__ A, const float* __restrict__ W,
    const float* __restrict__ bias, const float* __restrict__ aux,
    float* __restrict__ C, int M, int N, int K) {
  __shared__ unsigned short As[2][128][40];  // [plane][m][k]
  __shared__ unsigned short Bs[2][128][40];  // [plane][n][k]  (W transposed)
  int t = threadIdx.x;
  int lane = t & 63, wid = t >> 6;
  int wr = wid >> 1, wc = wid & 1;
  int row0 = blockIdx.y * 128, col0 = blockIdx.x * 128;

  f32x4 acc[4][4];
#pragma unroll
  for (int mi = 0; mi < 4; mi++)
#pragma unroll
    for (int ni = 0; ni < 4; ni++)
#pragma unroll
      for (int j = 0; j < 4; j++) acc[mi][ni][j] = 0.f;

  // staging roles
  int am = t >> 1;          // A row within tile (0..127)
  int ak = (t & 1) * 16;    // A k-offset (0 or 16)
  int bn = t & 127;         // B column within tile (0..127)
  int bk8 = (t >> 7) * 8;   // B k-offset base (0 or 8); iters add 0/16

  int fr = lane & 15, fq = lane >> 4;
  int fk = fq * 8;  // fragment k-element offset

  const float* aptr = A + (size_t)(row0 + am) * K + ak;
  const float* wptr = W + (size_t)bk8 * N + col0 + bn;

  // ---- prologue: load tile k0 = 0 ----
  float av[16], bv[16];
#pragma unroll
  for (int c = 0; c < 4; c++)
    *(float4*)&av[c * 4] = *(const float4*)&aptr[c * 4];
#pragma unroll
  for (int i = 0; i < 2; i++)
#pragma unroll
    for (int j = 0; j < 8; j++)
      bv[i * 8 + j] = wptr[(size_t)(i * 16 + j) * N];

  for (int k0 = 0; k0 < K; k0 += 32) {
    // ---- convert current tile to hi/lo planes (regs only) ----
    unsigned short ah[16], al[16], bh[16], bl[16];
#pragma unroll
    for (int e = 0; e < 16; e++) {
      ah[e] = f2bf(av[e]);
      al[e] = f2bf(av[e] - bf2f(ah[e]));
      bh[e] = f2bf(bv[e]);
      bl[e] = f2bf(bv[e] - bf2f(bh[e]));
    }

    __syncthreads();  // previous iteration's ds_reads complete

    *(uint4*)&As[0][am][ak + 0] = *(uint4*)&ah[0];
    *(uint4*)&As[0][am][ak + 8] = *(uint4*)&ah[8];
    *(uint4*)&As[1][am][ak + 0] = *(uint4*)&al[0];
    *(uint4*)&As[1][am][ak + 8] = *(uint4*)&al[8];
#pragma unroll
    for (int i = 0; i < 2; i++) {
      *(uint4*)&Bs[0][bn][bk8 + i * 16] = *(uint4*)&bh[i * 8];
      *(uint4*)&Bs[1][bn][bk8 + i * 16] = *(uint4*)&bl[i * 8];
    }

    __syncthreads();  // tile ready

    // ---- issue next tile's global loads (hide under MFMA phase) ----
    if (k0 + 32 < K) {
      const float* ap = aptr + (k0 + 32);
      const float* wp = wptr + (size_t)(k0 + 32) * N;
#pragma unroll
      for (int c = 0; c < 4; c++)
        *(float4*)&av[c * 4] = *(const float4*)&ap[c * 4];
#pragma unroll
      for (int i = 0; i < 2; i++)
#pragma unroll
        for (int j = 0; j < 8; j++)
          bv[i * 8 + j] = wp[(size_t)(i * 16 + j) * N];
    }

    // ---- fragments + MFMA ----
    short8 bfr[4][2];
#pragma unroll
    for (int ni = 0; ni < 4; ni++) {
      int brow = wc * 64 + ni * 16 + fr;
      bfr[ni][0] = *(const short8*)&Bs[0][brow][fk];
      bfr[ni][1] = *(const short8*)&Bs[1][brow][fk];
    }
#pragma unroll
    for (int mi = 0; mi < 4; mi++) {
      int arow = wr * 64 + mi * 16 + fr;
      short8 a_h = *(const short8*)&As[0][arow][fk];
      short8 a_l = *(const short8*)&As[1][arow][fk];
#pragma unroll
      for (int ni = 0; ni < 4; ni++) {
        acc[mi][ni] = __builtin_amdgcn_mfma_f32_16x16x32_bf16(
            a_h, bfr[ni][0], acc[mi][ni], 0, 0, 0);
        acc[mi][ni] = __builtin_amdgcn_mfma_f32_16x16x32_bf16(
            a_h, bfr[ni][1], acc[mi][ni], 0, 0, 0);
        acc[mi][ni] = __builtin_amdgcn_mfma_f32_16x16x32_bf16(
            a_l, bfr[ni][0], acc[mi][ni], 0, 0, 0);
      }
    }
  }

  // ---- epilogue ----
#pragma unroll
  for (int mi = 0; mi < 4; mi++) {
#pragma unroll
    for (int ni = 0; ni < 4; ni++) {
      int row = row0 + wr * 64 + mi * 16 + fq * 4;
      int col = col0 + wc * 64 + ni * 16 + fr;
      float bc = bias[col];
#pragma unroll
      for (int j = 0; j < 4; j++) {
        size_t idx = (size_t)(row + j) * N + col;
        float v = acc[mi][ni][j] + bc;
        if (EPI == 1) v += aux[idx];
        if (EPI == 2) {
          float u = aux[idx];
          v = (u / (1.f + expf(-u))) * v;
        }
        C[idx] = v;
      }
    }
  }
}

// ---------------------------------------------------------------------------
// RoPE cos/sin table: tab[l*64+i] = {cos(l/10000^(2i/128)), sin(...)}
// ---------------------------------------------------------------------------
__global__ __launch_bounds__(256) void rope_table_kernel(float* __restrict__ tab) {
  int idx = blockIdx.x * 256 + threadIdx.x;
  if (idx >= SEQ * 64) return;
  int l = idx >> 6, i = idx & 63;
  double div = pow(10000.0, (double)(2 * i) / (double)DH);
  double ang = (double)l / div;
  tab[idx * 2 + 0] = (float)cos(ang);
  tab[idx * 2 + 1] = (float)sin(ang);
}

// ---------------------------------------------------------------------------
// Gather Q per the reference's raw reshape + RoPE + softmax prescale.
// q[b,h,l2,d2] = qmat[b, h*128 + l2/16, (l2%16)*128 + d2]
// ---------------------------------------------------------------------------
__global__ __launch_bounds__(256) void gather_rope_q(
    const float* __restrict__ qmat, const float* __restrict__ tab,
    float* __restrict__ Qo) {
  int gid = blockIdx.x * 4 + (threadIdx.x >> 6);  // over B*NH*SEQ
  int lane = threadIdx.x & 63;
  int b = gid >> 15;
  int rem = gid & 32767;
  int h = rem >> 11, l2 = rem & 2047;
  int srow = h * 128 + (l2 >> 4);
  int scol = (l2 & 15) * 128;
  const float2* src = (const float2*)(qmat + ((size_t)b * SEQ + srow) * DM + scol);
  float2 v = src[lane];
  float2 cs = ((const float2*)tab)[l2 * 64 + lane];
  const float scale = 0.08838834764831845f;  // 1/sqrt(128)
  float2 o;
  o.x = (v.x * cs.x - v.y * cs.y) * scale;
  o.y = (v.x * cs.y + v.y * cs.x) * scale;
  ((float2*)(Qo + (size_t)gid * DH))[lane] = o;
}

// k/v[b,g,l2,d2] = mat[b, g*512 + l2/4, (l2%4)*128 + d2]; RoPE only on K.
template <bool ROPE>
__global__ __launch_bounds__(256) void gather_kv(
    const float* __restrict__ mat, const float* __restrict__ tab,
    float* __restrict__ out) {
  int gid = blockIdx.x * 4 + (threadIdx.x >> 6);  // over B*NG*SEQ
  int lane = threadIdx.x & 63;
  int b = gid >> 13;
  int rem = gid & 8191;
  int g = rem >> 11, l2 = rem & 2047;
  int srow = g * 512 + (l2 >> 2);
  int scol = (l2 & 3) * 128;
  const float2* src = (const float2*)(mat + ((size_t)b * SEQ + srow) * KVD + scol);
  float2 v = src[lane];
  float2 o;
  if (ROPE) {
    float2 cs = ((const float2*)tab)[l2 * 64 + lane];
    o.x = v.x * cs.x - v.y * cs.y;
    o.y = v.x * cs.y + v.y * cs.x;
  } else {
    o = v;
  }
  ((float2*)(out + (size_t)gid * DH))[lane] = o;
}

// ---------------------------------------------------------------------------
// Causal flash attention, fp32. Block = (q-tile of 32) x (b,h). 256 threads.
// Q is pre-scaled by 1/sqrt(DH).
// ---------------------------------------------------------------------------
__global__ __launch_bounds__(256) void attn_kernel(
    const float* __restrict__ Q, const float* __restrict__ K,
    const float* __restrict__ V, float* __restrict__ O) {
  constexpr int QT = 32, KT = 32, DP = DH + 4;
  __shared__ float Qs[QT][DP], Ks[KT][DP], Vs[KT][DP];
  __shared__ float Ss[QT][KT + 1];
  __shared__ float ms[QT], lsum[QT], alph[QT];
  int t = threadIdx.x;
  int bh = blockIdx.y;
  int q0 = blockIdx.x * QT;
  int g = (bh % NH) >> 2;  // head -> group (hpg = 4)
  const float* Qb = Q + ((size_t)bh * SEQ + q0) * DH;
  const float* Kb = K + ((size_t)((bh / NH) * NG + g) * SEQ) * DH;
  const float* Vb = V + ((size_t)((bh / NH) * NG + g) * SEQ) * DH;

#pragma unroll
  for (int r = 0; r < 4; r++) {
    int f4 = t + r * 256;
    int row = f4 >> 5, c4 = (f4 & 31) * 4;
    *(float4*)&Qs[row][c4] = *(const float4*)&Qb[(size_t)row * DH + c4];
  }
  if (t < QT) { ms[t] = -INFINITY; lsum[t] = 0.f; }
  float oacc[16];
#pragma unroll
  for (int i = 0; i < 16; i++) oacc[i] = 0.f;
  int r_own = t >> 3, c0 = (t & 7) * 16;

  int nkt = blockIdx.x + 1;
  for (int kt = 0; kt < nkt; kt++) {
    __syncthreads();
    const float* kbt = Kb + (size_t)kt * KT * DH;
    const float* vbt = Vb + (size_t)kt * KT * DH;
#pragma unroll
    for (int r = 0; r < 4; r++) {
      int f4 = t + r * 256;
      int row = f4 >> 5, c4 = (f4 & 31) * 4;
      *(float4*)&Ks[row][c4] = *(const float4*)&kbt[(size_t)row * DH + c4];
      *(float4*)&Vs[row][c4] = *(const float4*)&vbt[(size_t)row * DH + c4];
    }
    __syncthreads();
#pragma unroll
    for (int it = 0; it < 4; it++) {
      int p = t + it * 256;
      int i = p >> 5, j = p & 31;
      float acc = 0.f;
#pragma unroll
      for (int d = 0; d < DH; d += 4) {
        float4 qv = *(const float4*)&Qs[i][d];
        float4 kv = *(const float4*)&Ks[j][d];
        acc = fmaf(qv.x, kv.x, acc);
        acc = fmaf(qv.y, kv.y, acc);
        acc = fmaf(qv.z, kv.z, acc);
        acc = fmaf(qv.w, kv.w, acc);
      }
      int kj = kt * KT + j;
      Ss[i][j] = (kj <= q0 + i) ? acc : -INFINITY;
    }
    __syncthreads();
    if (t < QT) {
      float mold = ms[t], mmax = mold;
      for (int j = 0; j < KT; j++) mmax = fmaxf(mmax, Ss[t][j]);
      float al = expf(mold - mmax);
      float sum = 0.f;
      for (int j = 0; j < KT; j++) {
        float pv = expf(Ss[t][j] - mmax);
        Ss[t][j] = pv;
        sum += pv;
      }
      lsum[t] = lsum[t] * al + sum;
      ms[t] = mmax;
      alph[t] = al;
    }
    __syncthreads();
    float al = alph[r_own];
#pragma unroll
    for (int i = 0; i < 16; i++) oacc[i] *= al;
    for (int j = 0; j < KT; j++) {
      float pv = Ss[r_own][j];
#pragma unroll
      for (int tt = 0; tt < 16; tt += 4) {
        float4 vv = *(const float4*)&Vs[j][c0 + tt];
        oacc[tt + 0] = fmaf(pv, vv.x, oacc[tt + 0]);
        oacc[tt + 1] = fmaf(pv, vv.y, oacc[tt + 1]);
        oacc[tt + 2] = fmaf(pv, vv.z, oacc[tt + 2]);
        oacc[tt + 3] = fmaf(pv, vv.w, oacc[tt + 3]);
      }
    }
  }
  __syncthreads();
  float invl = 1.0f / lsum[r_own];
  float* ob = O + ((size_t)bh * SEQ + q0 + r_own) * DH + c0;
#pragma unroll
  for (int tt = 0; tt < 16; tt += 4) {
    float4 v;
    v.x = oacc[tt + 0] * invl; v.y = oacc[tt + 1] * invl;
    v.z = oacc[tt + 2] * invl; v.w = oacc[tt + 3] * invl;
    *(float4*)&ob[tt] = v;
  }
}

// ---------------------------------------------------------------------------
// Scatter O (b,h,l2,d2) back to (b,l,D) per the inverse raw-reshape.
// ---------------------------------------------------------------------------
__global__ __launch_bounds__(256) void scatter_o(const float* __restrict__ O,
                                                 float* __restrict__ attn) {
  size_t i4 = (size_t)blockIdx.x * 256 + threadIdx.x;
  size_t f = i4 * 4;
  int b = (int)(f >> 22);
  int rem = (int)(f & 4194303);
  int l = rem >> 11, d = rem & 2047;
  int c = l * 16 + (d >> 7);
  int h = c >> 11, l2 = c & 2047, d2 = d & 127;
  float4 v = *(const float4*)&O[(((size_t)b * NH + h) * SEQ + l2) * DH + d2];
  *(float4*)&attn[f] = v;
}

// ---------------------------------------------------------------------------
extern "C" void kernel_launch(void* const* d_in, const int* in_sizes, int n_in,
                              void* d_out, int out_size, void* d_ws,
                              size_t ws_size, hipStream_t stream) {
  // Workspace requirement: 56,885,248 floats = 227,540,992 bytes.
  // If the harness gives us less, bail out (validation will fail with a
  // fully-poisoned d_out, which is a diagnosable signal — NOT a crash).
  if (ws_size < 56885248ull * 4ull) return;

  const float* x  = (const float*)d_in[0];
  const float* g1 = (const float*)d_in[1];
  const float* wq = (const float*)d_in[2];
  const float* bq = (const float*)d_in[3];
  const float* wk = (const float*)d_in[4];
  const float* bk = (const float*)d_in[5];
  const float* wv = (const float*)d_in[6];
  const float* bv = (const float*)d_in[7];
  const float* wo = (const float*)d_in[8];
  const float* bo = (const float*)d_in[9];
  const float* g2 = (const float*)d_in[10];
  const float* w1 = (const float*)d_in[11];
  const float* b1 = (const float*)d_in[12];
  const float* wg = (const float*)d_in[13];
  const float* bg = (const float*)d_in[14];
  const float* w2 = (const float*)d_in[15];
  const float* b2 = (const float*)d_in[16];
  float* out = (float*)d_out;
  float* ws = (float*)d_ws;

  // workspace layout (floats); buffers reused across phases (227.5 MB total)
  float* buf_h = ws + 0;         // h (rms1)   -> later attn O
  float* buf_q = ws + 8388608;   // qmat       -> later attn-scattered -> h2
  float* buf_k = ws + 16777216;  // kmat
  float* buf_v = ws + 18874368;  // vmat
  float* buf_Q = ws + 20971520;  // Q (roped)  -> later x2
  float* buf_K = ws + 29360128;  // K (roped)
  float* buf_V = ws + 31457280;  // V
  float* buf_u = ws + 33554432;  // u = h2@w1+b1 -> m = silu(u)*(h2@wg+bg)
  float* tab   = ws + 56623104;  // rope table [262144]

  rope_table_kernel<<<(SEQ * 64 + 255) / 256, 256, 0, stream>>>(tab);
  rmsnorm_kernel<<<MROWS, 256, 0, stream>>>(x, g1, buf_h);

  gemm_bf16x3<0><<<dim3(DM / 128, MROWS / 128), 256, 0, stream>>>(
      buf_h, wq, bq, nullptr, buf_q, MROWS, DM, DM);
  gemm_bf16x3<0><<<dim3(KVD / 128, MROWS / 128), 256, 0, stream>>>(
      buf_h, wk, bk, nullptr, buf_k, MROWS, KVD, DM);
  gemm_bf16x3<0><<<dim3(KVD / 128, MROWS / 128), 256, 0, stream>>>(
      buf_h, wv, bv, nullptr, buf_v, MROWS, KVD, DM);

  gather_rope_q<<<(BATCH * NH * SEQ) / 4, 256, 0, stream>>>(buf_q, tab, buf_Q);
  gather_kv<true><<<(BATCH * NG * SEQ) / 4, 256, 0, stream>>>(buf_k, tab, buf_K);
  gather_kv<false><<<(BATCH * NG * SEQ) / 4, 256, 0, stream>>>(buf_v, tab, buf_V);

  attn_kernel<<<dim3(SEQ / 32, BATCH * NH), 256, 0, stream>>>(buf_Q, buf_K,
                                                              buf_V, buf_h);
  scatter_o<<<(MROWS * DM / 4) / 256, 256, 0, stream>>>(buf_h, buf_q);

  // x2 = x + attn @ wo + bo
  gemm_bf16x3<1><<<dim3(DM / 128, MROWS / 128), 256, 0, stream>>>(
      buf_q, wo, bo, x, buf_Q, MROWS, DM, DM);

  // h2 = rmsnorm(x2, g2)
  rmsnorm_kernel<<<MROWS, 256, 0, stream>>>(buf_Q, g2, buf_q);

  // u = h2@w1 + b1
  gemm_bf16x3<0><<<dim3(HDIM / 128, MROWS / 128), 256, 0, stream>>>(
      buf_q, w1, b1, nullptr, buf_u, MROWS, HDIM, DM);
  // m = silu(u) * (h2@wg + bg), in place into buf_u
  gemm_bf16x3<2><<<dim3(HDIM / 128, MROWS / 128), 256, 0, stream>>>(
      buf_q, wg, bg, buf_u, buf_u, MROWS, HDIM, DM);

  // out = x2 + m @ w2 + b2
  gemm_bf16x3<1><<<dim3(DM / 128, MROWS / 128), 256, 0, stream>>>(
      buf_u, w2, b2, buf_Q, out, MROWS, DM, HDIM);
}

// Round 11
// 2215.456 us; speedup vs baseline: 2.9760x; 2.9760x over previous
//
#include <hip/hip_runtime.h>
#include <math.h>

#define BATCH 2
#define SEQ 2048
#define DM 2048
#define NH 16
#define NG 4
#define DH 128
#define HDIM 5632
#define MROWS (BATCH * SEQ)
#define KVD (NG * DH) /* 512 */

typedef __attribute__((ext_vector_type(8))) short short8;
typedef __attribute__((ext_vector_type(4))) float f32x4;
typedef unsigned short ushortT;

__device__ __forceinline__ unsigned short f2bf(float x) {
  unsigned int u = __float_as_uint(x);
  u += 0x7FFFu + ((u >> 16) & 1u);  // round-to-nearest-even
  return (unsigned short)(u >> 16);
}
__device__ __forceinline__ float bf2f(unsigned short h) {
  return __uint_as_float(((unsigned int)h) << 16);
}

// ---------------------------------------------------------------------------
// RMSNorm: one block (256 threads) per row of 2048 floats
// ---------------------------------------------------------------------------
__global__ __launch_bounds__(256) void rmsnorm_kernel(
    const float* __restrict__ x, const float* __restrict__ g,
    float* __restrict__ out) {
  int row = blockIdx.x;
  const float4* xr = (const float4*)(x + (size_t)row * DM);
  float4* orow = (float4*)(out + (size_t)row * DM);
  const float4* g4 = (const float4*)g;
  int t = threadIdx.x;
  float4 a = xr[t];
  float4 b = xr[t + 256];
  float ss = a.x * a.x + a.y * a.y + a.z * a.z + a.w * a.w +
             b.x * b.x + b.y * b.y + b.z * b.z + b.w * b.w;
#pragma unroll
  for (int off = 32; off > 0; off >>= 1) ss += __shfl_xor(ss, off);
  __shared__ float red[4];
  if ((t & 63) == 0) red[t >> 6] = ss;
  __syncthreads();
  float tot = red[0] + red[1] + red[2] + red[3];
  float inv = rsqrtf(tot * (1.0f / DM) + 1e-6f);
  float4 ga = g4[t], gb = g4[t + 256];
  float4 oa, ob;
  oa.x = a.x * inv * ga.x; oa.y = a.y * inv * ga.y;
  oa.z = a.z * inv * ga.z; oa.w = a.w * inv * ga.w;
  ob.x = b.x * inv * gb.x; ob.y = b.y * inv * gb.y;
  ob.z = b.z * inv * gb.z; ob.w = b.w * inv * gb.w;
  orow[t] = oa;
  orow[t + 256] = ob;
}

// ---------------------------------------------------------------------------
// bf16x3 split-precision MFMA GEMM (validated R5): C = A@W + bias [+ epi]
//   EPI 0: +bias   EPI 1: +bias+aux   EPI 2: (acc+bias)*silu(aux)
// ---------------------------------------------------------------------------
template <int EPI>
__global__ __launch_bounds__(256) void gemm_bf16x3(
    const float* __restrict__ A, const float* __restrict__ W,
    const float* __restrict__ bias, const float* __restrict__ aux,
    float* __restrict__ C, int M, int N, int K) {
  __shared__ unsigned short As[2][128][40];  // [plane][m][k]
  __shared__ unsigned short Bs[2][128][40];  // [plane][n][k]  (W transposed)
  int t = threadIdx.x;
  int lane = t & 63, wid = t >> 6;
  int wr = wid >> 1, wc = wid & 1;
  int row0 = blockIdx.y * 128, col0 = blockIdx.x * 128;

  f32x4 acc[4][4];
#pragma unroll
  for (int mi = 0; mi < 4; mi++)
#pragma unroll
    for (int ni = 0; ni < 4; ni++)
#pragma unroll
      for (int j = 0; j < 4; j++) acc[mi][ni][j] = 0.f;

  int am = t >> 1;
  int ak = (t & 1) * 16;
  int bn = t & 127;
  int bk8 = (t >> 7) * 8;

  int fr = lane & 15, fq = lane >> 4;
  int fk = fq * 8;

  const float* aptr = A + (size_t)(row0 + am) * K + ak;
  const float* wptr = W + (size_t)bk8 * N + col0 + bn;

  float av[16], bv[16];
#pragma unroll
  for (int c = 0; c < 4; c++)
    *(float4*)&av[c * 4] = *(const float4*)&aptr[c * 4];
#pragma unroll
  for (int i = 0; i < 2; i++)
#pragma unroll
    for (int j = 0; j < 8; j++)
      bv[i * 8 + j] = wptr[(size_t)(i * 16 + j) * N];

  for (int k0 = 0; k0 < K; k0 += 32) {
    unsigned short ah[16], al[16], bh[16], bl[16];
#pragma unroll
    for (int e = 0; e < 16; e++) {
      ah[e] = f2bf(av[e]);
      al[e] = f2bf(av[e] - bf2f(ah[e]));
      bh[e] = f2bf(bv[e]);
      bl[e] = f2bf(bv[e] - bf2f(bh[e]));
    }

    __syncthreads();

    *(uint4*)&As[0][am][ak + 0] = *(uint4*)&ah[0];
    *(uint4*)&As[0][am][ak + 8] = *(uint4*)&ah[8];
    *(uint4*)&As[1][am][ak + 0] = *(uint4*)&al[0];
    *(uint4*)&As[1][am][ak + 8] = *(uint4*)&al[8];
#pragma unroll
    for (int i = 0; i < 2; i++) {
      *(uint4*)&Bs[0][bn][bk8 + i * 16] = *(uint4*)&bh[i * 8];
      *(uint4*)&Bs[1][bn][bk8 + i * 16] = *(uint4*)&bl[i * 8];
    }

    __syncthreads();

    if (k0 + 32 < K) {
      const float* ap = aptr + (k0 + 32);
      const float* wp = wptr + (size_t)(k0 + 32) * N;
#pragma unroll
      for (int c = 0; c < 4; c++)
        *(float4*)&av[c * 4] = *(const float4*)&ap[c * 4];
#pragma unroll
      for (int i = 0; i < 2; i++)
#pragma unroll
        for (int j = 0; j < 8; j++)
          bv[i * 8 + j] = wp[(size_t)(i * 16 + j) * N];
    }

    short8 bfr[4][2];
#pragma unroll
    for (int ni = 0; ni < 4; ni++) {
      int brow = wc * 64 + ni * 16 + fr;
      bfr[ni][0] = *(const short8*)&Bs[0][brow][fk];
      bfr[ni][1] = *(const short8*)&Bs[1][brow][fk];
    }
#pragma unroll
    for (int mi = 0; mi < 4; mi++) {
      int arow = wr * 64 + mi * 16 + fr;
      short8 a_h = *(const short8*)&As[0][arow][fk];
      short8 a_l = *(const short8*)&As[1][arow][fk];
#pragma unroll
      for (int ni = 0; ni < 4; ni++) {
        acc[mi][ni] = __builtin_amdgcn_mfma_f32_16x16x32_bf16(
            a_h, bfr[ni][0], acc[mi][ni], 0, 0, 0);
        acc[mi][ni] = __builtin_amdgcn_mfma_f32_16x16x32_bf16(
            a_h, bfr[ni][1], acc[mi][ni], 0, 0, 0);
        acc[mi][ni] = __builtin_amdgcn_mfma_f32_16x16x32_bf16(
            a_l, bfr[ni][0], acc[mi][ni], 0, 0, 0);
      }
    }
  }

#pragma unroll
  for (int mi = 0; mi < 4; mi++) {
#pragma unroll
    for (int ni = 0; ni < 4; ni++) {
      int row = row0 + wr * 64 + mi * 16 + fq * 4;
      int col = col0 + wc * 64 + ni * 16 + fr;
      float bc = bias[col];
#pragma unroll
      for (int j = 0; j < 4; j++) {
        size_t idx = (size_t)(row + j) * N + col;
        float v = acc[mi][ni][j] + bc;
        if (EPI == 1) v += aux[idx];
        if (EPI == 2) {
          float u = aux[idx];
          v = (u / (1.f + expf(-u))) * v;
        }
        C[idx] = v;
      }
    }
  }
}

// ---------------------------------------------------------------------------
// RoPE cos/sin table
// ---------------------------------------------------------------------------
__global__ __launch_bounds__(256) void rope_table_kernel(float* __restrict__ tab) {
  int idx = blockIdx.x * 256 + threadIdx.x;
  if (idx >= SEQ * 64) return;
  int l = idx >> 6, i = idx & 63;
  double div = pow(10000.0, (double)(2 * i) / (double)DH);
  double ang = (double)l / div;
  tab[idx * 2 + 0] = (float)cos(ang);
  tab[idx * 2 + 1] = (float)sin(ang);
}

// ---------------------------------------------------------------------------
// Gather Q (raw-reshape) + RoPE + 1/sqrt(DH) prescale -> bf16 hi/lo planes
// q[b,h,l2,d2] = qmat[b, h*128 + l2/16, (l2%16)*128 + d2]
// ---------------------------------------------------------------------------
__global__ __launch_bounds__(256) void gather_rope_q_bf(
    const float* __restrict__ qmat, const float* __restrict__ tab,
    ushortT* __restrict__ Qh, ushortT* __restrict__ Ql) {
  int gid = blockIdx.x * 4 + (threadIdx.x >> 6);  // over B*NH*SEQ
  int lane = threadIdx.x & 63;
  int b = gid >> 15;
  int rem = gid & 32767;
  int h = rem >> 11, l2 = rem & 2047;
  int srow = h * 128 + (l2 >> 4);
  int scol = (l2 & 15) * 128;
  const float2* src = (const float2*)(qmat + ((size_t)b * SEQ + srow) * DM + scol);
  float2 v = src[lane];
  float2 cs = ((const float2*)tab)[l2 * 64 + lane];
  const float scale = 0.08838834764831845f;  // 1/sqrt(128)
  float ox = (v.x * cs.x - v.y * cs.y) * scale;
  float oy = (v.x * cs.y + v.y * cs.x) * scale;
  ushortT hx = f2bf(ox), hy = f2bf(oy);
  ushortT lx = f2bf(ox - bf2f(hx)), ly = f2bf(oy - bf2f(hy));
  size_t o = (size_t)gid * DH + 2 * lane;
  Qh[o] = hx; Qh[o + 1] = hy;
  Ql[o] = lx; Ql[o + 1] = ly;
}

// K gather (raw-reshape) + RoPE -> bf16 hi/lo planes [b,g,l2,d]
__global__ __launch_bounds__(256) void gather_k_bf(
    const float* __restrict__ mat, const float* __restrict__ tab,
    ushortT* __restrict__ Kh, ushortT* __restrict__ Kl) {
  int gid = blockIdx.x * 4 + (threadIdx.x >> 6);  // over B*NG*SEQ
  int lane = threadIdx.x & 63;
  int b = gid >> 13;
  int rem = gid & 8191;
  int g = rem >> 11, l2 = rem & 2047;
  int srow = g * 512 + (l2 >> 2);
  int scol = (l2 & 3) * 128;
  const float2* src = (const float2*)(mat + ((size_t)b * SEQ + srow) * KVD + scol);
  float2 v = src[lane];
  float2 cs = ((const float2*)tab)[l2 * 64 + lane];
  float ox = v.x * cs.x - v.y * cs.y;
  float oy = v.x * cs.y + v.y * cs.x;
  ushortT hx = f2bf(ox), hy = f2bf(oy);
  ushortT lx = f2bf(ox - bf2f(hx)), ly = f2bf(oy - bf2f(hy));
  size_t o = (size_t)gid * DH + 2 * lane;
  Kh[o] = hx; Kh[o + 1] = hy;
  Kl[o] = lx; Kl[o + 1] = ly;
}

// ---------------------------------------------------------------------------
// V gather (raw-reshape) + TRANSPOSE -> Vt[b,g,d,l2] bf16 hi/lo planes.
// Tile: 64 l2 x 32 d via LDS.
// ---------------------------------------------------------------------------
__global__ __launch_bounds__(256) void gather_vt_bf(
    const float* __restrict__ vmat, ushortT* __restrict__ Vth,
    ushortT* __restrict__ Vtl) {
  __shared__ float Ls[64][33];
  int t = threadIdx.x;
  int bg = blockIdx.z;
  int b = bg >> 2, g = bg & 3;
  int l2base = blockIdx.x * 64, dbase = blockIdx.y * 32;

  int l2 = l2base + (t >> 2);
  int srow = g * 512 + (l2 >> 2);
  int scol = (l2 & 3) * 128 + dbase + (t & 3) * 8;
  const float* src = vmat + ((size_t)b * SEQ + srow) * KVD + scol;
  float4 v0 = *(const float4*)src;
  float4 v1 = *(const float4*)(src + 4);
  int lr = t >> 2, lc = (t & 3) * 8;
  Ls[lr][lc + 0] = v0.x; Ls[lr][lc + 1] = v0.y;
  Ls[lr][lc + 2] = v0.z; Ls[lr][lc + 3] = v0.w;
  Ls[lr][lc + 4] = v1.x; Ls[lr][lc + 5] = v1.y;
  Ls[lr][lc + 6] = v1.z; Ls[lr][lc + 7] = v1.w;
  __syncthreads();
  short8 hv, lv;
#pragma unroll
  for (int i = 0; i < 8; i++) {
    float v = Ls[(t & 7) * 8 + i][t >> 3];
    unsigned short h = f2bf(v);
    hv[i] = (short)h;
    lv[i] = (short)f2bf(v - bf2f(h));
  }
  size_t o = ((size_t)bg * DH + dbase + (t >> 3)) * SEQ + l2base + (t & 7) * 8;
  *(short8*)(Vth + o) = hv;
  *(short8*)(Vtl + o) = lv;
}

// ---------------------------------------------------------------------------
// MFMA flash attention (bf16x3). Block = 4 waves, Q-tile 64 (16 rows/wave),
// K-tile 32. Q frags in regs; K [kcol][d] and Vt [d][kcol] staged to LDS from
// pre-split global planes; online softmax in registers (shfl row-reduce);
// P transposed C-layout -> A-layout through tiny per-wave LDS buffer.
// ---------------------------------------------------------------------------
__global__ __launch_bounds__(256) void attn_mfma(
    const ushortT* __restrict__ Qh, const ushortT* __restrict__ Ql,
    const ushortT* __restrict__ Kh, const ushortT* __restrict__ Kl,
    const ushortT* __restrict__ Vth, const ushortT* __restrict__ Vtl,
    float* __restrict__ O) {
  __shared__ ushortT Ks[2][32][136];   // [plane][kcol][d]
  __shared__ ushortT Vts[2][128][40];  // [plane][d][kcol^swz]
  __shared__ ushortT Ps[4][2][16][40]; // [wave][plane][qrow][kcol]
  int t = threadIdx.x;
  int lane = t & 63, w = t >> 6;
  int fr = lane & 15, fq = lane >> 4;
  int bh = blockIdx.y;
  int bg = (bh >> 4) * NG + ((bh & 15) >> 2);
  int q0 = ((int)gridDim.x - 1 - (int)blockIdx.x) * 64;  // big tiles first

  // Q fragments (hi/lo): rows w*16+fr, k = ks*32 + fq*8 + e
  short8 qfh[4], qfl[4];
  {
    const ushortT* qs = Qh + ((size_t)bh * SEQ + q0 + w * 16 + fr) * DH + fq * 8;
    const ushortT* qs2 = Ql + ((size_t)bh * SEQ + q0 + w * 16 + fr) * DH + fq * 8;
#pragma unroll
    for (int ks = 0; ks < 4; ks++) {
      qfh[ks] = *(const short8*)(qs + ks * 32);
      qfl[ks] = *(const short8*)(qs2 + ks * 32);
    }
  }

  f32x4 oacc[8];
#pragma unroll
  for (int nt = 0; nt < 8; nt++)
#pragma unroll
    for (int j = 0; j < 4; j++) oacc[nt][j] = 0.f;
  float m[4], l[4];
#pragma unroll
  for (int j = 0; j < 4; j++) { m[j] = -INFINITY; l[j] = 0.f; }

  int nkt = q0 / 32 + 2;
  for (int kt = 0; kt < nkt; kt++) {
    // ---- staging: issue global loads early, write LDS after barrier ----
    int p = t >> 7, tt = t & 127;
    int kr = tt >> 2, cb = (tt & 3) * 32;
    const ushortT* ksp =
        (p ? Kl : Kh) + ((size_t)bg * SEQ + kt * 32 + kr) * DH + cb;
    uint4 k0 = *(const uint4*)(ksp + 0), k1 = *(const uint4*)(ksp + 8);
    uint4 k2 = *(const uint4*)(ksp + 16), k3 = *(const uint4*)(ksp + 24);
    const ushortT* vsp = (p ? Vtl : Vth) + ((size_t)bg * DH + tt) * SEQ + kt * 32;
    uint4 v0 = *(const uint4*)(vsp + 0), v1 = *(const uint4*)(vsp + 8);
    uint4 v2 = *(const uint4*)(vsp + 16), v3 = *(const uint4*)(vsp + 24);

    __syncthreads();  // prior tile's reads complete
    *(uint4*)&Ks[p][kr][cb + 0] = k0;
    *(uint4*)&Ks[p][kr][cb + 8] = k1;
    *(uint4*)&Ks[p][kr][cb + 16] = k2;
    *(uint4*)&Ks[p][kr][cb + 24] = k3;
    int xs = (tt & 3) << 3;  // col-swizzle key (d & 3)
    *(uint4*)&Vts[p][tt][0 ^ xs] = v0;
    *(uint4*)&Vts[p][tt][8 ^ xs] = v1;
    *(uint4*)&Vts[p][tt][16 ^ xs] = v2;
    *(uint4*)&Vts[p][tt][24 ^ xs] = v3;
    __syncthreads();  // tile ready

    // ---- QK^T: S[16x32] = Q(16x128) . K^T ----
    f32x4 sc[2];
#pragma unroll
    for (int ct = 0; ct < 2; ct++)
#pragma unroll
      for (int j = 0; j < 4; j++) sc[ct][j] = 0.f;
#pragma unroll
    for (int ct = 0; ct < 2; ct++)
#pragma unroll
      for (int ks = 0; ks < 4; ks++) {
        short8 kfh = *(const short8*)&Ks[0][ct * 16 + fr][ks * 32 + fq * 8];
        short8 kfl = *(const short8*)&Ks[1][ct * 16 + fr][ks * 32 + fq * 8];
        sc[ct] = __builtin_amdgcn_mfma_f32_16x16x32_bf16(qfh[ks], kfh, sc[ct], 0, 0, 0);
        sc[ct] = __builtin_amdgcn_mfma_f32_16x16x32_bf16(qfh[ks], kfl, sc[ct], 0, 0, 0);
        sc[ct] = __builtin_amdgcn_mfma_f32_16x16x32_bf16(qfl[ks], kfh, sc[ct], 0, 0, 0);
      }

    // ---- online softmax (rows fq*4+j, cols fr / 16+fr across 16 lanes) ----
    float alpha[4];
#pragma unroll
    for (int j = 0; j < 4; j++) {
      int qg = q0 + w * 16 + fq * 4 + j;
      float s0 = (kt * 32 + fr <= qg) ? sc[0][j] : -INFINITY;
      float s1 = (kt * 32 + 16 + fr <= qg) ? sc[1][j] : -INFINITY;
      float mx = fmaxf(s0, s1);
      mx = fmaxf(mx, __shfl_xor(mx, 1));
      mx = fmaxf(mx, __shfl_xor(mx, 2));
      mx = fmaxf(mx, __shfl_xor(mx, 4));
      mx = fmaxf(mx, __shfl_xor(mx, 8));
      float mn = fmaxf(m[j], mx);
      float al = expf(m[j] - mn);
      float p0 = expf(s0 - mn), p1 = expf(s1 - mn);
      float rs = p0 + p1;
      rs += __shfl_xor(rs, 1);
      rs += __shfl_xor(rs, 2);
      rs += __shfl_xor(rs, 4);
      rs += __shfl_xor(rs, 8);
      l[j] = l[j] * al + rs;
      m[j] = mn;
      alpha[j] = al;
      ushortT p0h = f2bf(p0), p1h = f2bf(p1);
      Ps[w][0][fq * 4 + j][fr] = p0h;
      Ps[w][0][fq * 4 + j][16 + fr] = p1h;
      Ps[w][1][fq * 4 + j][fr] = f2bf(p0 - bf2f(p0h));
      Ps[w][1][fq * 4 + j][16 + fr] = f2bf(p1 - bf2f(p1h));
    }
#pragma unroll
    for (int nt = 0; nt < 8; nt++) {
      oacc[nt][0] *= alpha[0];
      oacc[nt][1] *= alpha[1];
      oacc[nt][2] *= alpha[2];
      oacc[nt][3] *= alpha[3];
    }

    // ---- PV: O[16x128] += P(16x32) . V(32x128) ----
    short8 pah = *(const short8*)&Ps[w][0][fr][fq * 8];
    short8 pal = *(const short8*)&Ps[w][1][fr][fq * 8];
#pragma unroll
    for (int nt = 0; nt < 8; nt++) {
      int vr = nt * 16 + fr;
      int vc = (fq * 8) ^ ((fr & 3) << 3);
      short8 vfh = *(const short8*)&Vts[0][vr][vc];
      short8 vfl = *(const short8*)&Vts[1][vr][vc];
      oacc[nt] = __builtin_amdgcn_mfma_f32_16x16x32_bf16(pah, vfh, oacc[nt], 0, 0, 0);
      oacc[nt] = __builtin_amdgcn_mfma_f32_16x16x32_bf16(pah, vfl, oacc[nt], 0, 0, 0);
      oacc[nt] = __builtin_amdgcn_mfma_f32_16x16x32_bf16(pal, vfh, oacc[nt], 0, 0, 0);
    }
  }

  // ---- epilogue: O /= l ----
  float inv[4];
#pragma unroll
  for (int j = 0; j < 4; j++) inv[j] = 1.f / l[j];
  float* ob = O + ((size_t)bh * SEQ + q0 + w * 16 + fq * 4) * DH + fr;
#pragma unroll
  for (int nt = 0; nt < 8; nt++)
#pragma unroll
    for (int j = 0; j < 4; j++)
      ob[(size_t)j * DH + nt * 16] = oacc[nt][j] * inv[j];
}

// ---------------------------------------------------------------------------
// Scatter O (b,h,l2,d2) back to (b,l,D) per the inverse raw-reshape.
// ---------------------------------------------------------------------------
__global__ __launch_bounds__(256) void scatter_o(const float* __restrict__ O,
                                                 float* __restrict__ attn) {
  size_t i4 = (size_t)blockIdx.x * 256 + threadIdx.x;
  size_t f = i4 * 4;
  int b = (int)(f >> 22);
  int rem = (int)(f & 4194303);
  int l = rem >> 11, d = rem & 2047;
  int c = l * 16 + (d >> 7);
  int h = c >> 11, l2 = c & 2047, d2 = d & 127;
  float4 v = *(const float4*)&O[(((size_t)b * NH + h) * SEQ + l2) * DH + d2];
  *(float4*)&attn[f] = v;
}

// ---------------------------------------------------------------------------
extern "C" void kernel_launch(void* const* d_in, const int* in_sizes, int n_in,
                              void* d_out, int out_size, void* d_ws,
                              size_t ws_size, hipStream_t stream) {
  // Workspace requirement: 48,496,640 floats = 193,986,560 bytes.
  if (ws_size < 48496640ull * 4ull) return;

  const float* x  = (const float*)d_in[0];
  const float* g1 = (const float*)d_in[1];
  const float* wq = (const float*)d_in[2];
  const float* bq = (const float*)d_in[3];
  const float* wk = (const float*)d_in[4];
  const float* bk = (const float*)d_in[5];
  const float* wv = (const float*)d_in[6];
  const float* bv = (const float*)d_in[7];
  const float* wo = (const float*)d_in[8];
  const float* bo = (const float*)d_in[9];
  const float* g2 = (const float*)d_in[10];
  const float* w1 = (const float*)d_in[11];
  const float* b1 = (const float*)d_in[12];
  const float* wg = (const float*)d_in[13];
  const float* bg = (const float*)d_in[14];
  const float* w2 = (const float*)d_in[15];
  const float* b2 = (const float*)d_in[16];
  float* out = (float*)d_out;
  float* ws = (float*)d_ws;

  // workspace layout (float offsets), aliased by lifetime:
  float* buf_h  = ws + 0;         // h -> attn O -> h2
  float* buf_q  = ws + 8388608;   // qmat -> attn_l (scatter target)
  float* buf_k  = ws + 16777216;  // kmat (dies after gather_k)
  float* buf_v  = ws + 18874368;  // vmat (dies after gather_vt)
  float* buf_x2 = ws + 16777216;  // x2 (written after attn; aliases k/v)
  ushortT* Qh  = (ushortT*)(ws + 25165824);
  ushortT* Ql  = (ushortT*)(ws + 29360128);
  ushortT* Kh  = (ushortT*)(ws + 33554432);
  ushortT* Kl  = (ushortT*)(ws + 34603008);
  ushortT* Vth = (ushortT*)(ws + 35651584);
  ushortT* Vtl = (ushortT*)(ws + 36700160);
  float* buf_u = ws + 25165824;   // u/m (aliases planes; written after attn)
  float* tab   = ws + 48234496;   // rope table [262144]

  rope_table_kernel<<<(SEQ * 64 + 255) / 256, 256, 0, stream>>>(tab);
  rmsnorm_kernel<<<MROWS, 256, 0, stream>>>(x, g1, buf_h);

  gemm_bf16x3<0><<<dim3(DM / 128, MROWS / 128), 256, 0, stream>>>(
      buf_h, wq, bq, nullptr, buf_q, MROWS, DM, DM);
  gemm_bf16x3<0><<<dim3(KVD / 128, MROWS / 128), 256, 0, stream>>>(
      buf_h, wk, bk, nullptr, buf_k, MROWS, KVD, DM);
  gemm_bf16x3<0><<<dim3(KVD / 128, MROWS / 128), 256, 0, stream>>>(
      buf_h, wv, bv, nullptr, buf_v, MROWS, KVD, DM);

  gather_rope_q_bf<<<(BATCH * NH * SEQ) / 4, 256, 0, stream>>>(buf_q, tab, Qh, Ql);
  gather_k_bf<<<(BATCH * NG * SEQ) / 4, 256, 0, stream>>>(buf_k, tab, Kh, Kl);
  gather_vt_bf<<<dim3(SEQ / 64, DH / 32, BATCH * NG), 256, 0, stream>>>(
      buf_v, Vth, Vtl);

  attn_mfma<<<dim3(SEQ / 64, BATCH * NH), 256, 0, stream>>>(
      Qh, Ql, Kh, Kl, Vth, Vtl, buf_h);
  scatter_o<<<(MROWS * DM / 4) / 256, 256, 0, stream>>>(buf_h, buf_q);

  // x2 = x + attn @ wo + bo
  gemm_bf16x3<1><<<dim3(DM / 128, MROWS / 128), 256, 0, stream>>>(
      buf_q, wo, bo, x, buf_x2, MROWS, DM, DM);

  // h2 = rmsnorm(x2, g2)
  rmsnorm_kernel<<<MROWS, 256, 0, stream>>>(buf_x2, g2, buf_h);

  // u = h2@w1 + b1
  gemm_bf16x3<0><<<dim3(HDIM / 128, MROWS / 128), 256, 0, stream>>>(
      buf_h, w1, b1, nullptr, buf_u, MROWS, HDIM, DM);
  // m = silu(u) * (h2@wg + bg), in place
  gemm_bf16x3<2><<<dim3(HDIM / 128, MROWS / 128), 256, 0, stream>>>(
      buf_h, wg, bg, buf_u, buf_u, MROWS, HDIM, DM);

  // out = x2 + m @ w2 + b2
  gemm_bf16x3<1><<<dim3(DM / 128, MROWS / 128), 256, 0, stream>>>(
      buf_u, w2, b2, buf_x2, out, MROWS, DM, HDIM);
}

// Round 12
// 2026.004 us; speedup vs baseline: 3.2543x; 1.0935x over previous
//
#include <hip/hip_runtime.h>
#include <math.h>

#define BATCH 2
#define SEQ 2048
#define DM 2048
#define NH 16
#define NG 4
#define DH 128
#define HDIM 5632
#define MROWS (BATCH * SEQ)
#define KVD (NG * DH) /* 512 */

typedef __attribute__((ext_vector_type(8))) short short8;
typedef __attribute__((ext_vector_type(4))) float f32x4;
typedef __attribute__((ext_vector_type(4))) unsigned short us4;
typedef unsigned short ushortT;

__device__ __forceinline__ unsigned short f2bf(float x) {
  unsigned int u = __float_as_uint(x);
  u += 0x7FFFu + ((u >> 16) & 1u);  // round-to-nearest-even
  return (unsigned short)(u >> 16);
}
__device__ __forceinline__ float bf2f(unsigned short h) {
  return __uint_as_float(((unsigned int)h) << 16);
}

// ---------------------------------------------------------------------------
// RMSNorm -> bf16 hi/lo planes (h feeds only GEMMs). One block per row.
// ---------------------------------------------------------------------------
__global__ __launch_bounds__(256) void rmsnorm_planes(
    const float* __restrict__ x, const float* __restrict__ g,
    ushortT* __restrict__ Ah, ushortT* __restrict__ Al) {
  int row = blockIdx.x;
  const float4* xr = (const float4*)(x + (size_t)row * DM);
  const float4* g4 = (const float4*)g;
  int t = threadIdx.x;
  float4 a = xr[t];
  float4 b = xr[t + 256];
  float ss = a.x * a.x + a.y * a.y + a.z * a.z + a.w * a.w +
             b.x * b.x + b.y * b.y + b.z * b.z + b.w * b.w;
#pragma unroll
  for (int off = 32; off > 0; off >>= 1) ss += __shfl_xor(ss, off);
  __shared__ float red[4];
  if ((t & 63) == 0) red[t >> 6] = ss;
  __syncthreads();
  float tot = red[0] + red[1] + red[2] + red[3];
  float inv = rsqrtf(tot * (1.0f / DM) + 1e-6f);
  float4 ga = g4[t], gb = g4[t + 256];
  float va[4] = {a.x * inv * ga.x, a.y * inv * ga.y, a.z * inv * ga.z,
                 a.w * inv * ga.w};
  float vb[4] = {b.x * inv * gb.x, b.y * inv * gb.y, b.z * inv * gb.z,
                 b.w * inv * gb.w};
  us4 ha, la, hb, lb;
#pragma unroll
  for (int i = 0; i < 4; i++) {
    ushortT h = f2bf(va[i]);
    ha[i] = h; la[i] = f2bf(va[i] - bf2f(h));
    h = f2bf(vb[i]);
    hb[i] = h; lb[i] = f2bf(vb[i] - bf2f(h));
  }
  size_t o = (size_t)row * DM + 4 * t;
  *(us4*)&Ah[o] = ha; *(us4*)&Al[o] = la;
  *(us4*)&Ah[o + 1024] = hb; *(us4*)&Al[o + 1024] = lb;
}

// ---------------------------------------------------------------------------
// Weight split+transpose: W [K][N] fp32 -> Wth/Wtl [N][K] bf16 planes.
// 64x64 tiles via LDS. grid(N/64, K/64).
// ---------------------------------------------------------------------------
__global__ __launch_bounds__(256) void split_wt(
    const float* __restrict__ W, ushortT* __restrict__ Wth,
    ushortT* __restrict__ Wtl, int K, int N) {
  __shared__ float Ls[64][65];
  int t = threadIdx.x;
  int nb = blockIdx.x * 64, kb = blockIdx.y * 64;
  int lr = t >> 4, lc = (t & 15) * 4;
#pragma unroll
  for (int r = 0; r < 4; r++) {
    float4 v = *(const float4*)&W[(size_t)(kb + lr + r * 16) * N + nb + lc];
    Ls[lr + r * 16][lc + 0] = v.x;
    Ls[lr + r * 16][lc + 1] = v.y;
    Ls[lr + r * 16][lc + 2] = v.z;
    Ls[lr + r * 16][lc + 3] = v.w;
  }
  __syncthreads();
  int nr = t >> 2, kc = (t & 3) * 16;
  ushortT hv[16], lv[16];
#pragma unroll
  for (int i = 0; i < 16; i++) {
    float v = Ls[kc + i][nr];
    hv[i] = f2bf(v);
    lv[i] = f2bf(v - bf2f(hv[i]));
  }
  size_t o = (size_t)(nb + nr) * K + kb + kc;
  *(uint4*)&Wth[o] = *(uint4*)&hv[0];
  *(uint4*)&Wth[o + 8] = *(uint4*)&hv[8];
  *(uint4*)&Wtl[o] = *(uint4*)&lv[0];
  *(uint4*)&Wtl[o + 8] = *(uint4*)&lv[8];
}

// ---------------------------------------------------------------------------
// Plane-consuming bf16x3 MFMA GEMM. A planes [M][K]; W planes [N][K].
//   EPI 0: Cf = acc+bias
//   EPI 1: Cf = acc+bias+auxf
//   EPI 2: (Ch,Cl) = planes(acc+bias)
//   EPI 3: (Ch,Cl) = planes( (acc+bias) * silu(auxh+auxl) )   [in-place ok]
// 128x128 tile, BK=32, 4 waves (2x2), frag layout identical to validated R5.
// ---------------------------------------------------------------------------
template <int EPI>
__global__ __launch_bounds__(256) void gemm_pl(
    const ushortT* __restrict__ Ah, const ushortT* __restrict__ Al,
    const ushortT* __restrict__ Wth, const ushortT* __restrict__ Wtl,
    const float* __restrict__ bias, const float* __restrict__ auxf,
    const ushortT* __restrict__ auxh, const ushortT* __restrict__ auxl,
    float* __restrict__ Cf, ushortT* __restrict__ Ch,
    ushortT* __restrict__ Cl, int M, int N, int K) {
  __shared__ ushortT As[2][128][40];
  __shared__ ushortT Bs[2][128][40];
  int t = threadIdx.x;
  int lane = t & 63, wid = t >> 6;
  int wr = wid >> 1, wc = wid & 1;
  int row0 = blockIdx.y * 128, col0 = blockIdx.x * 128;

  f32x4 acc[4][4];
#pragma unroll
  for (int mi = 0; mi < 4; mi++)
#pragma unroll
    for (int ni = 0; ni < 4; ni++)
#pragma unroll
      for (int j = 0; j < 4; j++) acc[mi][ni][j] = 0.f;

  int am = t >> 1, ak = (t & 1) * 16;
  int bn = t & 127, bk = (t >> 7) * 16;
  int fr = lane & 15, fq = lane >> 4;
  int fk = fq * 8;

  const ushortT* a0 = Ah + (size_t)(row0 + am) * K + ak;
  const ushortT* a1 = Al + (size_t)(row0 + am) * K + ak;
  const ushortT* b0 = Wth + (size_t)(col0 + bn) * K + bk;
  const ushortT* b1 = Wtl + (size_t)(col0 + bn) * K + bk;

  uint4 ra0 = *(const uint4*)(a0), ra1 = *(const uint4*)(a0 + 8);
  uint4 ra2 = *(const uint4*)(a1), ra3 = *(const uint4*)(a1 + 8);
  uint4 rb0 = *(const uint4*)(b0), rb1 = *(const uint4*)(b0 + 8);
  uint4 rb2 = *(const uint4*)(b1), rb3 = *(const uint4*)(b1 + 8);

  for (int k0 = 0; k0 < K; k0 += 32) {
    __syncthreads();  // previous iteration's ds_reads complete
    *(uint4*)&As[0][am][ak + 0] = ra0;
    *(uint4*)&As[0][am][ak + 8] = ra1;
    *(uint4*)&As[1][am][ak + 0] = ra2;
    *(uint4*)&As[1][am][ak + 8] = ra3;
    *(uint4*)&Bs[0][bn][bk + 0] = rb0;
    *(uint4*)&Bs[0][bn][bk + 8] = rb1;
    *(uint4*)&Bs[1][bn][bk + 0] = rb2;
    *(uint4*)&Bs[1][bn][bk + 8] = rb3;
    __syncthreads();  // tile ready

    if (k0 + 32 < K) {  // prefetch next tile under MFMA phase
      ra0 = *(const uint4*)(a0 + k0 + 32);
      ra1 = *(const uint4*)(a0 + k0 + 40);
      ra2 = *(const uint4*)(a1 + k0 + 32);
      ra3 = *(const uint4*)(a1 + k0 + 40);
      rb0 = *(const uint4*)(b0 + k0 + 32);
      rb1 = *(const uint4*)(b0 + k0 + 40);
      rb2 = *(const uint4*)(b1 + k0 + 32);
      rb3 = *(const uint4*)(b1 + k0 + 40);
    }

    short8 bfr[4][2];
#pragma unroll
    for (int ni = 0; ni < 4; ni++) {
      int brow = wc * 64 + ni * 16 + fr;
      bfr[ni][0] = *(const short8*)&Bs[0][brow][fk];
      bfr[ni][1] = *(const short8*)&Bs[1][brow][fk];
    }
#pragma unroll
    for (int mi = 0; mi < 4; mi++) {
      int arow = wr * 64 + mi * 16 + fr;
      short8 a_h = *(const short8*)&As[0][arow][fk];
      short8 a_l = *(const short8*)&As[1][arow][fk];
#pragma unroll
      for (int ni = 0; ni < 4; ni++) {
        acc[mi][ni] = __builtin_amdgcn_mfma_f32_16x16x32_bf16(
            a_h, bfr[ni][0], acc[mi][ni], 0, 0, 0);
        acc[mi][ni] = __builtin_amdgcn_mfma_f32_16x16x32_bf16(
            a_h, bfr[ni][1], acc[mi][ni], 0, 0, 0);
        acc[mi][ni] = __builtin_amdgcn_mfma_f32_16x16x32_bf16(
            a_l, bfr[ni][0], acc[mi][ni], 0, 0, 0);
      }
    }
  }

#pragma unroll
  for (int mi = 0; mi < 4; mi++) {
#pragma unroll
    for (int ni = 0; ni < 4; ni++) {
      int row = row0 + wr * 64 + mi * 16 + fq * 4;
      int col = col0 + wc * 64 + ni * 16 + fr;
      float bc = bias[col];
#pragma unroll
      for (int j = 0; j < 4; j++) {
        size_t idx = (size_t)(row + j) * N + col;
        float v = acc[mi][ni][j] + bc;
        if (EPI == 1) v += auxf[idx];
        if (EPI == 3) {
          float u = bf2f(auxh[idx]) + bf2f(auxl[idx]);
          v = v * (u / (1.f + expf(-u)));
        }
        if (EPI <= 1) {
          Cf[idx] = v;
        } else {
          ushortT h = f2bf(v);
          Ch[idx] = h;
          Cl[idx] = f2bf(v - bf2f(h));
        }
      }
    }
  }
}

// ---------------------------------------------------------------------------
// RoPE cos/sin table
// ---------------------------------------------------------------------------
__global__ __launch_bounds__(256) void rope_table_kernel(float* __restrict__ tab) {
  int idx = blockIdx.x * 256 + threadIdx.x;
  if (idx >= SEQ * 64) return;
  int l = idx >> 6, i = idx & 63;
  double div = pow(10000.0, (double)(2 * i) / (double)DH);
  double ang = (double)l / div;
  tab[idx * 2 + 0] = (float)cos(ang);
  tab[idx * 2 + 1] = (float)sin(ang);
}

// ---------------------------------------------------------------------------
// Gather Q (raw-reshape) + RoPE + prescale (1/sqrt(DH) * log2(e)) -> planes
// ---------------------------------------------------------------------------
__global__ __launch_bounds__(256) void gather_rope_q_bf(
    const float* __restrict__ qmat, const float* __restrict__ tab,
    ushortT* __restrict__ Qh, ushortT* __restrict__ Ql) {
  int gid = blockIdx.x * 4 + (threadIdx.x >> 6);
  int lane = threadIdx.x & 63;
  int b = gid >> 15;
  int rem = gid & 32767;
  int h = rem >> 11, l2 = rem & 2047;
  int srow = h * 128 + (l2 >> 4);
  int scol = (l2 & 15) * 128;
  const float2* src = (const float2*)(qmat + ((size_t)b * SEQ + srow) * DM + scol);
  float2 v = src[lane];
  float2 cs = ((const float2*)tab)[l2 * 64 + lane];
  const float scale = (float)(0.08838834764831845 * 1.4426950408889634);
  float ox = (v.x * cs.x - v.y * cs.y) * scale;
  float oy = (v.x * cs.y + v.y * cs.x) * scale;
  ushortT hx = f2bf(ox), hy = f2bf(oy);
  ushortT lx = f2bf(ox - bf2f(hx)), ly = f2bf(oy - bf2f(hy));
  size_t o = (size_t)gid * DH + 2 * lane;
  Qh[o] = hx; Qh[o + 1] = hy;
  Ql[o] = lx; Ql[o + 1] = ly;
}

// K gather (raw-reshape) + RoPE -> planes
__global__ __launch_bounds__(256) void gather_k_bf(
    const float* __restrict__ mat, const float* __restrict__ tab,
    ushortT* __restrict__ Kh, ushortT* __restrict__ Kl) {
  int gid = blockIdx.x * 4 + (threadIdx.x >> 6);
  int lane = threadIdx.x & 63;
  int b = gid >> 13;
  int rem = gid & 8191;
  int g = rem >> 11, l2 = rem & 2047;
  int srow = g * 512 + (l2 >> 2);
  int scol = (l2 & 3) * 128;
  const float2* src = (const float2*)(mat + ((size_t)b * SEQ + srow) * KVD + scol);
  float2 v = src[lane];
  float2 cs = ((const float2*)tab)[l2 * 64 + lane];
  float ox = v.x * cs.x - v.y * cs.y;
  float oy = v.x * cs.y + v.y * cs.x;
  ushortT hx = f2bf(ox), hy = f2bf(oy);
  ushortT lx = f2bf(ox - bf2f(hx)), ly = f2bf(oy - bf2f(hy));
  size_t o = (size_t)gid * DH + 2 * lane;
  Kh[o] = hx; Kh[o + 1] = hy;
  Kl[o] = lx; Kl[o + 1] = ly;
}

// V gather (raw-reshape) + TRANSPOSE -> Vt[b,g,d,l2] planes
__global__ __launch_bounds__(256) void gather_vt_bf(
    const float* __restrict__ vmat, ushortT* __restrict__ Vth,
    ushortT* __restrict__ Vtl) {
  __shared__ float Ls[64][33];
  int t = threadIdx.x;
  int bg = blockIdx.z;
  int b = bg >> 2, g = bg & 3;
  int l2base = blockIdx.x * 64, dbase = blockIdx.y * 32;
  int l2 = l2base + (t >> 2);
  int srow = g * 512 + (l2 >> 2);
  int scol = (l2 & 3) * 128 + dbase + (t & 3) * 8;
  const float* src = vmat + ((size_t)b * SEQ + srow) * KVD + scol;
  float4 v0 = *(const float4*)src;
  float4 v1 = *(const float4*)(src + 4);
  int lr = t >> 2, lc = (t & 3) * 8;
  Ls[lr][lc + 0] = v0.x; Ls[lr][lc + 1] = v0.y;
  Ls[lr][lc + 2] = v0.z; Ls[lr][lc + 3] = v0.w;
  Ls[lr][lc + 4] = v1.x; Ls[lr][lc + 5] = v1.y;
  Ls[lr][lc + 6] = v1.z; Ls[lr][lc + 7] = v1.w;
  __syncthreads();
  short8 hv, lv;
#pragma unroll
  for (int i = 0; i < 8; i++) {
    float v = Ls[(t & 7) * 8 + i][t >> 3];
    unsigned short h = f2bf(v);
    hv[i] = (short)h;
    lv[i] = (short)f2bf(v - bf2f(h));
  }
  size_t o = ((size_t)bg * DH + dbase + (t >> 3)) * SEQ + l2base + (t & 7) * 8;
  *(short8*)(Vth + o) = hv;
  *(short8*)(Vtl + o) = lv;
}

// ---------------------------------------------------------------------------
// MFMA flash attention. Softmax in base-2 (Q pre-scaled by log2e); P single
// bf16 plane (P in [0,1], slack demonstrated); K,V bf16x3/x2 as before.
// ---------------------------------------------------------------------------
__global__ __launch_bounds__(256) void attn_mfma(
    const ushortT* __restrict__ Qh, const ushortT* __restrict__ Ql,
    const ushortT* __restrict__ Kh, const ushortT* __restrict__ Kl,
    const ushortT* __restrict__ Vth, const ushortT* __restrict__ Vtl,
    float* __restrict__ O) {
  __shared__ ushortT Ks[2][32][136];   // [plane][kcol][d]
  __shared__ ushortT Vts[2][128][40];  // [plane][d][kcol^swz]
  __shared__ ushortT Ps[4][16][40];    // [wave][qrow][kcol] (hi plane only)
  int t = threadIdx.x;
  int lane = t & 63, w = t >> 6;
  int fr = lane & 15, fq = lane >> 4;
  int bh = blockIdx.y;
  int bg = (bh >> 4) * NG + ((bh & 15) >> 2);
  int q0 = ((int)gridDim.x - 1 - (int)blockIdx.x) * 64;  // big tiles first

  short8 qfh[4], qfl[4];
  {
    const ushortT* qs = Qh + ((size_t)bh * SEQ + q0 + w * 16 + fr) * DH + fq * 8;
    const ushortT* qs2 = Ql + ((size_t)bh * SEQ + q0 + w * 16 + fr) * DH + fq * 8;
#pragma unroll
    for (int ks = 0; ks < 4; ks++) {
      qfh[ks] = *(const short8*)(qs + ks * 32);
      qfl[ks] = *(const short8*)(qs2 + ks * 32);
    }
  }

  f32x4 oacc[8];
#pragma unroll
  for (int nt = 0; nt < 8; nt++)
#pragma unroll
    for (int j = 0; j < 4; j++) oacc[nt][j] = 0.f;
  float m[4], l[4];
#pragma unroll
  for (int j = 0; j < 4; j++) { m[j] = -INFINITY; l[j] = 0.f; }

  int nkt = q0 / 32 + 2;
  for (int kt = 0; kt < nkt; kt++) {
    int p = t >> 7, tt = t & 127;
    int kr = tt >> 2, cb = (tt & 3) * 32;
    const ushortT* ksp =
        (p ? Kl : Kh) + ((size_t)bg * SEQ + kt * 32 + kr) * DH + cb;
    uint4 k0 = *(const uint4*)(ksp + 0), k1 = *(const uint4*)(ksp + 8);
    uint4 k2 = *(const uint4*)(ksp + 16), k3 = *(const uint4*)(ksp + 24);
    const ushortT* vsp = (p ? Vtl : Vth) + ((size_t)bg * DH + tt) * SEQ + kt * 32;
    uint4 v0 = *(const uint4*)(vsp + 0), v1 = *(const uint4*)(vsp + 8);
    uint4 v2 = *(const uint4*)(vsp + 16), v3 = *(const uint4*)(vsp + 24);

    __syncthreads();
    *(uint4*)&Ks[p][kr][cb + 0] = k0;
    *(uint4*)&Ks[p][kr][cb + 8] = k1;
    *(uint4*)&Ks[p][kr][cb + 16] = k2;
    *(uint4*)&Ks[p][kr][cb + 24] = k3;
    int xs = (tt & 3) << 3;
    *(uint4*)&Vts[p][tt][0 ^ xs] = v0;
    *(uint4*)&Vts[p][tt][8 ^ xs] = v1;
    *(uint4*)&Vts[p][tt][16 ^ xs] = v2;
    *(uint4*)&Vts[p][tt][24 ^ xs] = v3;
    __syncthreads();

    // QK^T
    f32x4 sc[2];
#pragma unroll
    for (int ct = 0; ct < 2; ct++)
#pragma unroll
      for (int j = 0; j < 4; j++) sc[ct][j] = 0.f;
#pragma unroll
    for (int ct = 0; ct < 2; ct++)
#pragma unroll
      for (int ks = 0; ks < 4; ks++) {
        short8 kfh = *(const short8*)&Ks[0][ct * 16 + fr][ks * 32 + fq * 8];
        short8 kfl = *(const short8*)&Ks[1][ct * 16 + fr][ks * 32 + fq * 8];
        sc[ct] = __builtin_amdgcn_mfma_f32_16x16x32_bf16(qfh[ks], kfh, sc[ct], 0, 0, 0);
        sc[ct] = __builtin_amdgcn_mfma_f32_16x16x32_bf16(qfh[ks], kfl, sc[ct], 0, 0, 0);
        sc[ct] = __builtin_amdgcn_mfma_f32_16x16x32_bf16(qfl[ks], kfh, sc[ct], 0, 0, 0);
      }

    // online softmax in base-2
    float alpha[4];
#pragma unroll
    for (int j = 0; j < 4; j++) {
      int qg = q0 + w * 16 + fq * 4 + j;
      float s0 = (kt * 32 + fr <= qg) ? sc[0][j] : -INFINITY;
      float s1 = (kt * 32 + 16 + fr <= qg) ? sc[1][j] : -INFINITY;
      float mx = fmaxf(s0, s1);
      mx = fmaxf(mx, __shfl_xor(mx, 1));
      mx = fmaxf(mx, __shfl_xor(mx, 2));
      mx = fmaxf(mx, __shfl_xor(mx, 4));
      mx = fmaxf(mx, __shfl_xor(mx, 8));
      float mn = fmaxf(m[j], mx);
      float al = exp2f(m[j] - mn);
      float p0 = exp2f(s0 - mn), p1 = exp2f(s1 - mn);
      float rs = p0 + p1;
      rs += __shfl_xor(rs, 1);
      rs += __shfl_xor(rs, 2);
      rs += __shfl_xor(rs, 4);
      rs += __shfl_xor(rs, 8);
      l[j] = l[j] * al + rs;
      m[j] = mn;
      alpha[j] = al;
      Ps[w][fq * 4 + j][fr] = f2bf(p0);
      Ps[w][fq * 4 + j][16 + fr] = f2bf(p1);
    }
#pragma unroll
    for (int nt = 0; nt < 8; nt++) {
      oacc[nt][0] *= alpha[0];
      oacc[nt][1] *= alpha[1];
      oacc[nt][2] *= alpha[2];
      oacc[nt][3] *= alpha[3];
    }

    // PV (single P plane x dual V planes)
    short8 pah = *(const short8*)&Ps[w][fr][fq * 8];
#pragma unroll
    for (int nt = 0; nt < 8; nt++) {
      int vr = nt * 16 + fr;
      int vc = (fq * 8) ^ ((fr & 3) << 3);
      short8 vfh = *(const short8*)&Vts[0][vr][vc];
      short8 vfl = *(const short8*)&Vts[1][vr][vc];
      oacc[nt] = __builtin_amdgcn_mfma_f32_16x16x32_bf16(pah, vfh, oacc[nt], 0, 0, 0);
      oacc[nt] = __builtin_amdgcn_mfma_f32_16x16x32_bf16(pah, vfl, oacc[nt], 0, 0, 0);
    }
  }

  float inv[4];
#pragma unroll
  for (int j = 0; j < 4; j++) inv[j] = 1.f / l[j];
  float* ob = O + ((size_t)bh * SEQ + q0 + w * 16 + fq * 4) * DH + fr;
#pragma unroll
  for (int nt = 0; nt < 8; nt++)
#pragma unroll
    for (int j = 0; j < 4; j++)
      ob[(size_t)j * DH + nt * 16] = oacc[nt][j] * inv[j];
}

// ---------------------------------------------------------------------------
// Scatter O (b,h,l2,d2) -> (b,l,D) planes (feeds wo-GEMM only).
// ---------------------------------------------------------------------------
__global__ __launch_bounds__(256) void scatter_o_planes(
    const float* __restrict__ O, ushortT* __restrict__ Sh,
    ushortT* __restrict__ Sl) {
  size_t i4 = (size_t)blockIdx.x * 256 + threadIdx.x;
  size_t f = i4 * 4;
  int b = (int)(f >> 22);
  int rem = (int)(f & 4194303);
  int l = rem >> 11, d = rem & 2047;
  int c = l * 16 + (d >> 7);
  int h = c >> 11, l2 = c & 2047, d2 = d & 127;
  float4 v = *(const float4*)&O[(((size_t)b * NH + h) * SEQ + l2) * DH + d2];
  float vv[4] = {v.x, v.y, v.z, v.w};
  us4 hv, lv;
#pragma unroll
  for (int i = 0; i < 4; i++) {
    ushortT h16 = f2bf(vv[i]);
    hv[i] = h16;
    lv[i] = f2bf(vv[i] - bf2f(h16));
  }
  *(us4*)&Sh[f] = hv;
  *(us4*)&Sl[f] = lv;
}

// ---------------------------------------------------------------------------
extern "C" void kernel_launch(void* const* d_in, const int* in_sizes, int n_in,
                              void* d_out, int out_size, void* d_ws,
                              size_t ws_size, hipStream_t stream) {
  // Workspace: 53,739,520 floats = 214,958,080 bytes (<= 227.5MB proven in R5).
  if (ws_size < 53739520ull * 4ull) return;

  const float* x  = (const float*)d_in[0];
  const float* g1 = (const float*)d_in[1];
  const float* wq = (const float*)d_in[2];
  const float* bq = (const float*)d_in[3];
  const float* wk = (const float*)d_in[4];
  const float* bk = (const float*)d_in[5];
  const float* wv = (const float*)d_in[6];
  const float* bv = (const float*)d_in[7];
  const float* wo = (const float*)d_in[8];
  const float* bo = (const float*)d_in[9];
  const float* g2 = (const float*)d_in[10];
  const float* w1 = (const float*)d_in[11];
  const float* b1 = (const float*)d_in[12];
  const float* wg = (const float*)d_in[13];
  const float* bg = (const float*)d_in[14];
  const float* w2 = (const float*)d_in[15];
  const float* b2 = (const float*)d_in[16];
  float* out = (float*)d_out;
  float* ws = (float*)d_ws;

  // regions (float offsets), aliased by lifetime
  ushortT* WTh = (ushortT*)(ws + 0);          // weight-plane scratch, 11.5M f
  ushortT* Hh  = (ushortT*)(ws + 11534336);   // h / h2 planes (8.4M f)
  ushortT* Hl  = Hh + 8388608;
  float* qmat  = ws + 19922944;               // qmat -> O -> u/m planes
  float* kmat  = ws + 28311552;
  float* vmat  = ws + 30408704;
  ushortT* Qh  = (ushortT*)(ws + 32505856);   // Q planes -> scatter planes -> (m tail)
  ushortT* Ql  = Qh + 8388608;
  ushortT* Kh  = (ushortT*)(ws + 40894464);
  ushortT* Kl  = Kh + 2097152;
  ushortT* Vth = (ushortT*)(ws + 42991616);
  ushortT* Vtl = Vth + 2097152;
  float* x2    = ws + 45088768;               // 8.4M f
  float* tab   = ws + 53477376;               // 262144 f
  float* O     = qmat;                        // attn out reuses qmat
  ushortT* Sh  = Qh;                          // scatter planes reuse Q planes
  ushortT* Sl  = Sh + 8388608;
  ushortT* Uh  = (ushortT*)qmat;              // u planes (23.07M f region)
  ushortT* Ul  = Uh + 23068672;               // m planes written in-place over u

  rope_table_kernel<<<(SEQ * 64 + 255) / 256, 256, 0, stream>>>(tab);
  rmsnorm_planes<<<MROWS, 256, 0, stream>>>(x, g1, Hh, Hl);

  // QKV projections
  split_wt<<<dim3(DM / 64, DM / 64), 256, 0, stream>>>(wq, WTh, WTh + DM * DM, DM, DM);
  gemm_pl<0><<<dim3(DM / 128, MROWS / 128), 256, 0, stream>>>(
      Hh, Hl, WTh, WTh + DM * DM, bq, nullptr, nullptr, nullptr, qmat, nullptr,
      nullptr, MROWS, DM, DM);
  split_wt<<<dim3(KVD / 64, DM / 64), 256, 0, stream>>>(wk, WTh, WTh + DM * KVD, DM, KVD);
  gemm_pl<0><<<dim3(KVD / 128, MROWS / 128), 256, 0, stream>>>(
      Hh, Hl, WTh, WTh + DM * KVD, bk, nullptr, nullptr, nullptr, kmat, nullptr,
      nullptr, MROWS, KVD, DM);
  split_wt<<<dim3(KVD / 64, DM / 64), 256, 0, stream>>>(wv, WTh, WTh + DM * KVD, DM, KVD);
  gemm_pl<0><<<dim3(KVD / 128, MROWS / 128), 256, 0, stream>>>(
      Hh, Hl, WTh, WTh + DM * KVD, bv, nullptr, nullptr, nullptr, vmat, nullptr,
      nullptr, MROWS, KVD, DM);

  gather_rope_q_bf<<<(BATCH * NH * SEQ) / 4, 256, 0, stream>>>(qmat, tab, Qh, Ql);
  gather_k_bf<<<(BATCH * NG * SEQ) / 4, 256, 0, stream>>>(kmat, tab, Kh, Kl);
  gather_vt_bf<<<dim3(SEQ / 64, DH / 32, BATCH * NG), 256, 0, stream>>>(vmat, Vth, Vtl);

  attn_mfma<<<dim3(SEQ / 64, BATCH * NH), 256, 0, stream>>>(Qh, Ql, Kh, Kl,
                                                            Vth, Vtl, O);
  scatter_o_planes<<<(MROWS * DM / 4) / 256, 256, 0, stream>>>(O, Sh, Sl);

  // x2 = x + attn @ wo + bo
  split_wt<<<dim3(DM / 64, DM / 64), 256, 0, stream>>>(wo, WTh, WTh + DM * DM, DM, DM);
  gemm_pl<1><<<dim3(DM / 128, MROWS / 128), 256, 0, stream>>>(
      Sh, Sl, WTh, WTh + DM * DM, bo, x, nullptr, nullptr, x2, nullptr,
      nullptr, MROWS, DM, DM);

  // h2 planes
  rmsnorm_planes<<<MROWS, 256, 0, stream>>>(x2, g2, Hh, Hl);

  // u = h2@w1 + b1 (planes out)
  split_wt<<<dim3(HDIM / 64, DM / 64), 256, 0, stream>>>(w1, WTh, WTh + DM * HDIM, DM, HDIM);
  gemm_pl<2><<<dim3(HDIM / 128, MROWS / 128), 256, 0, stream>>>(
      Hh, Hl, WTh, WTh + DM * HDIM, b1, nullptr, nullptr, nullptr, nullptr, Uh,
      Ul, MROWS, HDIM, DM);
  // m = silu(u) * (h2@wg + bg)   (planes out, in-place over u)
  split_wt<<<dim3(HDIM / 64, DM / 64), 256, 0, stream>>>(wg, WTh, WTh + DM * HDIM, DM, HDIM);
  gemm_pl<3><<<dim3(HDIM / 128, MROWS / 128), 256, 0, stream>>>(
      Hh, Hl, WTh, WTh + DM * HDIM, bg, nullptr, Uh, Ul, nullptr, Uh, Ul,
      MROWS, HDIM, DM);

  // out = x2 + m @ w2 + b2
  split_wt<<<dim3(DM / 64, HDIM / 64), 256, 0, stream>>>(w2, WTh, WTh + HDIM * DM, HDIM, DM);
  gemm_pl<1><<<dim3(DM / 128, MROWS / 128), 256, 0, stream>>>(
      Uh, Ul, WTh, WTh + HDIM * DM, b2, x2, nullptr, nullptr, out, nullptr,
      nullptr, MROWS, DM, HDIM);
}

// Round 13
// 1854.470 us; speedup vs baseline: 3.5553x; 1.0925x over previous
//
#include <hip/hip_runtime.h>
#include <math.h>

#define BATCH 2
#define SEQ 2048
#define DM 2048
#define NH 16
#define NG 4
#define DH 128
#define HDIM 5632
#define MROWS (BATCH * SEQ)
#define KVD (NG * DH)   /* 512 */
#define QKVD 3072       /* DM + 2*KVD */

typedef __attribute__((ext_vector_type(8))) short short8;
typedef __attribute__((ext_vector_type(4))) float f32x4;
typedef __attribute__((ext_vector_type(4))) unsigned short us4;
typedef unsigned short ushortT;

__device__ __forceinline__ unsigned short f2bf(float x) {
  unsigned int u = __float_as_uint(x);
  u += 0x7FFFu + ((u >> 16) & 1u);  // round-to-nearest-even
  return (unsigned short)(u >> 16);
}
__device__ __forceinline__ float bf2f(unsigned short h) {
  return __uint_as_float(((unsigned int)h) << 16);
}

// ---------------------------------------------------------------------------
// RMSNorm -> bf16 hi/lo planes. One block per row.
// ---------------------------------------------------------------------------
__global__ __launch_bounds__(256) void rmsnorm_planes(
    const float* __restrict__ x, const float* __restrict__ g,
    ushortT* __restrict__ Ah, ushortT* __restrict__ Al) {
  int row = blockIdx.x;
  const float4* xr = (const float4*)(x + (size_t)row * DM);
  const float4* g4 = (const float4*)g;
  int t = threadIdx.x;
  float4 a = xr[t];
  float4 b = xr[t + 256];
  float ss = a.x * a.x + a.y * a.y + a.z * a.z + a.w * a.w +
             b.x * b.x + b.y * b.y + b.z * b.z + b.w * b.w;
#pragma unroll
  for (int off = 32; off > 0; off >>= 1) ss += __shfl_xor(ss, off);
  __shared__ float red[4];
  if ((t & 63) == 0) red[t >> 6] = ss;
  __syncthreads();
  float tot = red[0] + red[1] + red[2] + red[3];
  float inv = rsqrtf(tot * (1.0f / DM) + 1e-6f);
  float4 ga = g4[t], gb = g4[t + 256];
  float va[4] = {a.x * inv * ga.x, a.y * inv * ga.y, a.z * inv * ga.z,
                 a.w * inv * ga.w};
  float vb[4] = {b.x * inv * gb.x, b.y * inv * gb.y, b.z * inv * gb.z,
                 b.w * inv * gb.w};
  us4 ha, la, hb, lb;
#pragma unroll
  for (int i = 0; i < 4; i++) {
    ushortT h = f2bf(va[i]);
    ha[i] = h; la[i] = f2bf(va[i] - bf2f(h));
    h = f2bf(vb[i]);
    hb[i] = h; lb[i] = f2bf(vb[i] - bf2f(h));
  }
  size_t o = (size_t)row * DM + 4 * t;
  *(us4*)&Ah[o] = ha; *(us4*)&Al[o] = la;
  *(us4*)&Ah[o + 1024] = hb; *(us4*)&Al[o + 1024] = lb;
}

// ---------------------------------------------------------------------------
// Weight split+transpose: W [K][N] fp32 -> Wth/Wtl [N][K] bf16 planes.
// ---------------------------------------------------------------------------
__global__ __launch_bounds__(256) void split_wt(
    const float* __restrict__ W, ushortT* __restrict__ Wth,
    ushortT* __restrict__ Wtl, int K, int N) {
  __shared__ float Ls[64][65];
  int t = threadIdx.x;
  int nb = blockIdx.x * 64, kb = blockIdx.y * 64;
  int lr = t >> 4, lc = (t & 15) * 4;
#pragma unroll
  for (int r = 0; r < 4; r++) {
    float4 v = *(const float4*)&W[(size_t)(kb + lr + r * 16) * N + nb + lc];
    Ls[lr + r * 16][lc + 0] = v.x;
    Ls[lr + r * 16][lc + 1] = v.y;
    Ls[lr + r * 16][lc + 2] = v.z;
    Ls[lr + r * 16][lc + 3] = v.w;
  }
  __syncthreads();
  int nr = t >> 2, kc = (t & 3) * 16;
  ushortT hv[16], lv[16];
#pragma unroll
  for (int i = 0; i < 16; i++) {
    float v = Ls[kc + i][nr];
    hv[i] = f2bf(v);
    lv[i] = f2bf(v - bf2f(hv[i]));
  }
  size_t o = (size_t)(nb + nr) * K + kb + kc;
  *(uint4*)&Wth[o] = *(uint4*)&hv[0];
  *(uint4*)&Wth[o + 8] = *(uint4*)&hv[8];
  *(uint4*)&Wtl[o] = *(uint4*)&lv[0];
  *(uint4*)&Wtl[o + 8] = *(uint4*)&lv[8];
}

// Concat bias for fused QKV
__global__ __launch_bounds__(256) void bias_cat(
    const float* __restrict__ bq, const float* __restrict__ bk,
    const float* __restrict__ bv, float* __restrict__ dst) {
  int t = blockIdx.x * 256 + threadIdx.x;
  if (t >= QKVD) return;
  dst[t] = (t < DM) ? bq[t] : ((t < DM + KVD) ? bk[t - DM] : bv[t - DM - KVD]);
}

// ---------------------------------------------------------------------------
// Plane-consuming bf16x3 MFMA GEMM (validated R12). A [M][K]; W [N][K] planes.
//   EPI 0: Cf = acc+bias        EPI 1: Cf = acc+bias+auxf
// ---------------------------------------------------------------------------
template <int EPI>
__global__ __launch_bounds__(256) void gemm_pl(
    const ushortT* __restrict__ Ah, const ushortT* __restrict__ Al,
    const ushortT* __restrict__ Wth, const ushortT* __restrict__ Wtl,
    const float* __restrict__ bias, const float* __restrict__ auxf,
    float* __restrict__ Cf, int M, int N, int K) {
  __shared__ ushortT As[2][128][40];
  __shared__ ushortT Bs[2][128][40];
  int t = threadIdx.x;
  int lane = t & 63, wid = t >> 6;
  int wr = wid >> 1, wc = wid & 1;
  int row0 = blockIdx.y * 128, col0 = blockIdx.x * 128;

  f32x4 acc[4][4];
#pragma unroll
  for (int mi = 0; mi < 4; mi++)
#pragma unroll
    for (int ni = 0; ni < 4; ni++)
#pragma unroll
      for (int j = 0; j < 4; j++) acc[mi][ni][j] = 0.f;

  int am = t >> 1, ak = (t & 1) * 16;
  int bn = t & 127, bk = (t >> 7) * 16;
  int fr = lane & 15, fq = lane >> 4;
  int fk = fq * 8;

  const ushortT* a0 = Ah + (size_t)(row0 + am) * K + ak;
  const ushortT* a1 = Al + (size_t)(row0 + am) * K + ak;
  const ushortT* b0 = Wth + (size_t)(col0 + bn) * K + bk;
  const ushortT* b1 = Wtl + (size_t)(col0 + bn) * K + bk;

  uint4 ra0 = *(const uint4*)(a0), ra1 = *(const uint4*)(a0 + 8);
  uint4 ra2 = *(const uint4*)(a1), ra3 = *(const uint4*)(a1 + 8);
  uint4 rb0 = *(const uint4*)(b0), rb1 = *(const uint4*)(b0 + 8);
  uint4 rb2 = *(const uint4*)(b1), rb3 = *(const uint4*)(b1 + 8);

  for (int k0 = 0; k0 < K; k0 += 32) {
    __syncthreads();
    *(uint4*)&As[0][am][ak + 0] = ra0;
    *(uint4*)&As[0][am][ak + 8] = ra1;
    *(uint4*)&As[1][am][ak + 0] = ra2;
    *(uint4*)&As[1][am][ak + 8] = ra3;
    *(uint4*)&Bs[0][bn][bk + 0] = rb0;
    *(uint4*)&Bs[0][bn][bk + 8] = rb1;
    *(uint4*)&Bs[1][bn][bk + 0] = rb2;
    *(uint4*)&Bs[1][bn][bk + 8] = rb3;
    __syncthreads();

    if (k0 + 32 < K) {
      ra0 = *(const uint4*)(a0 + k0 + 32);
      ra1 = *(const uint4*)(a0 + k0 + 40);
      ra2 = *(const uint4*)(a1 + k0 + 32);
      ra3 = *(const uint4*)(a1 + k0 + 40);
      rb0 = *(const uint4*)(b0 + k0 + 32);
      rb1 = *(const uint4*)(b0 + k0 + 40);
      rb2 = *(const uint4*)(b1 + k0 + 32);
      rb3 = *(const uint4*)(b1 + k0 + 40);
    }

    short8 bfr[4][2];
#pragma unroll
    for (int ni = 0; ni < 4; ni++) {
      int brow = wc * 64 + ni * 16 + fr;
      bfr[ni][0] = *(const short8*)&Bs[0][brow][fk];
      bfr[ni][1] = *(const short8*)&Bs[1][brow][fk];
    }
#pragma unroll
    for (int mi = 0; mi < 4; mi++) {
      int arow = wr * 64 + mi * 16 + fr;
      short8 a_h = *(const short8*)&As[0][arow][fk];
      short8 a_l = *(const short8*)&As[1][arow][fk];
#pragma unroll
      for (int ni = 0; ni < 4; ni++) {
        acc[mi][ni] = __builtin_amdgcn_mfma_f32_16x16x32_bf16(
            a_h, bfr[ni][0], acc[mi][ni], 0, 0, 0);
        acc[mi][ni] = __builtin_amdgcn_mfma_f32_16x16x32_bf16(
            a_h, bfr[ni][1], acc[mi][ni], 0, 0, 0);
        acc[mi][ni] = __builtin_amdgcn_mfma_f32_16x16x32_bf16(
            a_l, bfr[ni][0], acc[mi][ni], 0, 0, 0);
      }
    }
  }

#pragma unroll
  for (int mi = 0; mi < 4; mi++) {
#pragma unroll
    for (int ni = 0; ni < 4; ni++) {
      int row = row0 + wr * 64 + mi * 16 + fq * 4;
      int col = col0 + wc * 64 + ni * 16 + fr;
      float bc = bias[col];
#pragma unroll
      for (int j = 0; j < 4; j++) {
        size_t idx = (size_t)(row + j) * N + col;
        float v = acc[mi][ni][j] + bc;
        if (EPI == 1) v += auxf[idx];  // store depends on load -> ordered
        Cf[idx] = v;
      }
    }
  }
}

// ---------------------------------------------------------------------------
// Dual-B FFN GEMM: m = silu(A@W1+b1) * (A@Wg+bg), planes out.
// 512 threads = 8 waves (2 row-halves x 4 col-quarters); per wave 64x32 per
// output. BK=32, 2-barrier, full register prefetch.
// ---------------------------------------------------------------------------
__global__ __launch_bounds__(512) void gemm_dual(
    const ushortT* __restrict__ Ah, const ushortT* __restrict__ Al,
    const ushortT* __restrict__ W1h, const ushortT* __restrict__ W1l,
    const ushortT* __restrict__ W2h, const ushortT* __restrict__ W2l,
    const float* __restrict__ b1, const float* __restrict__ bg,
    ushortT* __restrict__ Mh, ushortT* __restrict__ Ml, int M, int N, int K) {
  __shared__ ushortT As[2][128][40];
  __shared__ ushortT B1s[2][128][40];
  __shared__ ushortT B2s[2][128][40];
  int t = threadIdx.x;
  int lane = t & 63, wid = t >> 6;
  int wr = wid >> 2, wc = wid & 3;
  int row0 = blockIdx.y * 128, col0 = blockIdx.x * 128;

  f32x4 accu[4][2], accg[4][2];
#pragma unroll
  for (int mi = 0; mi < 4; mi++)
#pragma unroll
    for (int ni = 0; ni < 2; ni++)
#pragma unroll
      for (int j = 0; j < 4; j++) { accu[mi][ni][j] = 0.f; accg[mi][ni][j] = 0.f; }

  int p = t >> 8, tt = t & 255;
  int am = tt >> 1, ak = (tt & 1) * 16;
  int fr = lane & 15, fq = lane >> 4;
  int fk = fq * 8;

  const ushortT* ap = (p ? Al : Ah) + (size_t)(row0 + am) * K + ak;
  const ushortT* b1p = (p ? W1l : W1h) + (size_t)(col0 + am) * K + ak;
  const ushortT* b2p = (p ? W2l : W2h) + (size_t)(col0 + am) * K + ak;

  uint4 ra0 = *(const uint4*)(ap), ra1 = *(const uint4*)(ap + 8);
  uint4 rb0 = *(const uint4*)(b1p), rb1 = *(const uint4*)(b1p + 8);
  uint4 rc0 = *(const uint4*)(b2p), rc1 = *(const uint4*)(b2p + 8);

  for (int k0 = 0; k0 < K; k0 += 32) {
    __syncthreads();
    *(uint4*)&As[p][am][ak + 0] = ra0;
    *(uint4*)&As[p][am][ak + 8] = ra1;
    *(uint4*)&B1s[p][am][ak + 0] = rb0;
    *(uint4*)&B1s[p][am][ak + 8] = rb1;
    *(uint4*)&B2s[p][am][ak + 0] = rc0;
    *(uint4*)&B2s[p][am][ak + 8] = rc1;
    __syncthreads();

    if (k0 + 32 < K) {
      ra0 = *(const uint4*)(ap + k0 + 32);
      ra1 = *(const uint4*)(ap + k0 + 40);
      rb0 = *(const uint4*)(b1p + k0 + 32);
      rb1 = *(const uint4*)(b1p + k0 + 40);
      rc0 = *(const uint4*)(b2p + k0 + 32);
      rc1 = *(const uint4*)(b2p + k0 + 40);
    }

    short8 b1f[2][2], b2f[2][2];
#pragma unroll
    for (int ni = 0; ni < 2; ni++) {
      int brow = wc * 32 + ni * 16 + fr;
      b1f[ni][0] = *(const short8*)&B1s[0][brow][fk];
      b1f[ni][1] = *(const short8*)&B1s[1][brow][fk];
      b2f[ni][0] = *(const short8*)&B2s[0][brow][fk];
      b2f[ni][1] = *(const short8*)&B2s[1][brow][fk];
    }
#pragma unroll
    for (int mi = 0; mi < 4; mi++) {
      int arow = wr * 64 + mi * 16 + fr;
      short8 a_h = *(const short8*)&As[0][arow][fk];
      short8 a_l = *(const short8*)&As[1][arow][fk];
#pragma unroll
      for (int ni = 0; ni < 2; ni++) {
        accu[mi][ni] = __builtin_amdgcn_mfma_f32_16x16x32_bf16(
            a_h, b1f[ni][0], accu[mi][ni], 0, 0, 0);
        accu[mi][ni] = __builtin_amdgcn_mfma_f32_16x16x32_bf16(
            a_h, b1f[ni][1], accu[mi][ni], 0, 0, 0);
        accu[mi][ni] = __builtin_amdgcn_mfma_f32_16x16x32_bf16(
            a_l, b1f[ni][0], accu[mi][ni], 0, 0, 0);
        accg[mi][ni] = __builtin_amdgcn_mfma_f32_16x16x32_bf16(
            a_h, b2f[ni][0], accg[mi][ni], 0, 0, 0);
        accg[mi][ni] = __builtin_amdgcn_mfma_f32_16x16x32_bf16(
            a_h, b2f[ni][1], accg[mi][ni], 0, 0, 0);
        accg[mi][ni] = __builtin_amdgcn_mfma_f32_16x16x32_bf16(
            a_l, b2f[ni][0], accg[mi][ni], 0, 0, 0);
      }
    }
  }

#pragma unroll
  for (int mi = 0; mi < 4; mi++) {
#pragma unroll
    for (int ni = 0; ni < 2; ni++) {
      int row = row0 + wr * 64 + mi * 16 + fq * 4;
      int col = col0 + wc * 32 + ni * 16 + fr;
      float b1c = b1[col], bgc = bg[col];
#pragma unroll
      for (int j = 0; j < 4; j++) {
        size_t idx = (size_t)(row + j) * N + col;
        float u = accu[mi][ni][j] + b1c;
        float g = accg[mi][ni][j] + bgc;
        float v = (u / (1.f + expf(-u))) * g;
        ushortT h = f2bf(v);
        Mh[idx] = h;
        Ml[idx] = f2bf(v - bf2f(h));
      }
    }
  }
}

// ---------------------------------------------------------------------------
// RoPE cos/sin table
// ---------------------------------------------------------------------------
__global__ __launch_bounds__(256) void rope_table_kernel(float* __restrict__ tab) {
  int idx = blockIdx.x * 256 + threadIdx.x;
  if (idx >= SEQ * 64) return;
  int l = idx >> 6, i = idx & 63;
  double div = pow(10000.0, (double)(2 * i) / (double)DH);
  double ang = (double)l / div;
  tab[idx * 2 + 0] = (float)cos(ang);
  tab[idx * 2 + 1] = (float)sin(ang);
}

// ---------------------------------------------------------------------------
// Gather Q from fused qkv (stride QKVD) + RoPE + prescale -> planes
// ---------------------------------------------------------------------------
__global__ __launch_bounds__(256) void gather_rope_q_bf(
    const float* __restrict__ qkv, const float* __restrict__ tab,
    ushortT* __restrict__ Qh, ushortT* __restrict__ Ql) {
  int gid = blockIdx.x * 4 + (threadIdx.x >> 6);
  int lane = threadIdx.x & 63;
  int b = gid >> 15;
  int rem = gid & 32767;
  int h = rem >> 11, l2 = rem & 2047;
  int srow = h * 128 + (l2 >> 4);
  int scol = (l2 & 15) * 128;
  const float2* src =
      (const float2*)(qkv + ((size_t)b * SEQ + srow) * QKVD + scol);
  float2 v = src[lane];
  float2 cs = ((const float2*)tab)[l2 * 64 + lane];
  const float scale = (float)(0.08838834764831845 * 1.4426950408889634);
  float ox = (v.x * cs.x - v.y * cs.y) * scale;
  float oy = (v.x * cs.y + v.y * cs.x) * scale;
  ushortT hx = f2bf(ox), hy = f2bf(oy);
  ushortT lx = f2bf(ox - bf2f(hx)), ly = f2bf(oy - bf2f(hy));
  size_t o = (size_t)gid * DH + 2 * lane;
  Qh[o] = hx; Qh[o + 1] = hy;
  Ql[o] = lx; Ql[o + 1] = ly;
}

// K gather from fused qkv (+DM col offset) + RoPE -> planes
__global__ __launch_bounds__(256) void gather_k_bf(
    const float* __restrict__ qkv, const float* __restrict__ tab,
    ushortT* __restrict__ Kh, ushortT* __restrict__ Kl) {
  int gid = blockIdx.x * 4 + (threadIdx.x >> 6);
  int lane = threadIdx.x & 63;
  int b = gid >> 13;
  int rem = gid & 8191;
  int g = rem >> 11, l2 = rem & 2047;
  int srow = g * 512 + (l2 >> 2);
  int scol = (l2 & 3) * 128;
  const float2* src =
      (const float2*)(qkv + ((size_t)b * SEQ + srow) * QKVD + DM + scol);
  float2 v = src[lane];
  float2 cs = ((const float2*)tab)[l2 * 64 + lane];
  float ox = v.x * cs.x - v.y * cs.y;
  float oy = v.x * cs.y + v.y * cs.x;
  ushortT hx = f2bf(ox), hy = f2bf(oy);
  ushortT lx = f2bf(ox - bf2f(hx)), ly = f2bf(oy - bf2f(hy));
  size_t o = (size_t)gid * DH + 2 * lane;
  Kh[o] = hx; Kh[o + 1] = hy;
  Kl[o] = lx; Kl[o + 1] = ly;
}

// V gather from fused qkv (+DM+KVD col offset) + TRANSPOSE -> Vt planes
__global__ __launch_bounds__(256) void gather_vt_bf(
    const float* __restrict__ qkv, ushortT* __restrict__ Vth,
    ushortT* __restrict__ Vtl) {
  __shared__ float Ls[64][33];
  int t = threadIdx.x;
  int bg = blockIdx.z;
  int b = bg >> 2, g = bg & 3;
  int l2base = blockIdx.x * 64, dbase = blockIdx.y * 32;
  int l2 = l2base + (t >> 2);
  int srow = g * 512 + (l2 >> 2);
  int scol = (l2 & 3) * 128 + dbase + (t & 3) * 8;
  const float* src = qkv + ((size_t)b * SEQ + srow) * QKVD + DM + KVD + scol;
  float4 v0 = *(const float4*)src;
  float4 v1 = *(const float4*)(src + 4);
  int lr = t >> 2, lc = (t & 3) * 8;
  Ls[lr][lc + 0] = v0.x; Ls[lr][lc + 1] = v0.y;
  Ls[lr][lc + 2] = v0.z; Ls[lr][lc + 3] = v0.w;
  Ls[lr][lc + 4] = v1.x; Ls[lr][lc + 5] = v1.y;
  Ls[lr][lc + 6] = v1.z; Ls[lr][lc + 7] = v1.w;
  __syncthreads();
  short8 hv, lv;
#pragma unroll
  for (int i = 0; i < 8; i++) {
    float v = Ls[(t & 7) * 8 + i][t >> 3];
    unsigned short h = f2bf(v);
    hv[i] = (short)h;
    lv[i] = (short)f2bf(v - bf2f(h));
  }
  size_t o = ((size_t)bg * DH + dbase + (t >> 3)) * SEQ + l2base + (t & 7) * 8;
  *(short8*)(Vth + o) = hv;
  *(short8*)(Vtl + o) = lv;
}

// ---------------------------------------------------------------------------
// MFMA flash attention (base-2 softmax, single P plane) with K/V register
// prefetch: next tile's loads issue right after "tile ready" so HBM/L2
// latency hides under QK^T+softmax+PV.
// ---------------------------------------------------------------------------
__global__ __launch_bounds__(256) void attn_mfma(
    const ushortT* __restrict__ Qh, const ushortT* __restrict__ Ql,
    const ushortT* __restrict__ Kh, const ushortT* __restrict__ Kl,
    const ushortT* __restrict__ Vth, const ushortT* __restrict__ Vtl,
    float* __restrict__ O) {
  __shared__ ushortT Ks[2][32][136];
  __shared__ ushortT Vts[2][128][40];
  __shared__ ushortT Ps[4][16][40];
  int t = threadIdx.x;
  int lane = t & 63, w = t >> 6;
  int fr = lane & 15, fq = lane >> 4;
  int bh = blockIdx.y;
  int bg = (bh >> 4) * NG + ((bh & 15) >> 2);
  int q0 = ((int)gridDim.x - 1 - (int)blockIdx.x) * 64;  // big tiles first

  short8 qfh[4], qfl[4];
  {
    const ushortT* qs = Qh + ((size_t)bh * SEQ + q0 + w * 16 + fr) * DH + fq * 8;
    const ushortT* qs2 = Ql + ((size_t)bh * SEQ + q0 + w * 16 + fr) * DH + fq * 8;
#pragma unroll
    for (int ks = 0; ks < 4; ks++) {
      qfh[ks] = *(const short8*)(qs + ks * 32);
      qfl[ks] = *(const short8*)(qs2 + ks * 32);
    }
  }

  f32x4 oacc[8];
#pragma unroll
  for (int nt = 0; nt < 8; nt++)
#pragma unroll
    for (int j = 0; j < 4; j++) oacc[nt][j] = 0.f;
  float m[4], l[4];
#pragma unroll
  for (int j = 0; j < 4; j++) { m[j] = -INFINITY; l[j] = 0.f; }

  int p = t >> 7, tt = t & 127;
  int kr = tt >> 2, cb = (tt & 3) * 32;
  const ushortT* kbase = (p ? Kl : Kh) + ((size_t)bg * SEQ + kr) * DH + cb;
  const ushortT* vbase = (p ? Vtl : Vth) + ((size_t)bg * DH + tt) * SEQ;
  int xs = (tt & 3) << 3;

  // prologue: load tile 0
  uint4 rk0 = *(const uint4*)(kbase + 0), rk1 = *(const uint4*)(kbase + 8);
  uint4 rk2 = *(const uint4*)(kbase + 16), rk3 = *(const uint4*)(kbase + 24);
  uint4 rv0 = *(const uint4*)(vbase + 0), rv1 = *(const uint4*)(vbase + 8);
  uint4 rv2 = *(const uint4*)(vbase + 16), rv3 = *(const uint4*)(vbase + 24);

  int nkt = q0 / 32 + 2;
  for (int kt = 0; kt < nkt; kt++) {
    __syncthreads();  // prior tile's reads complete
    *(uint4*)&Ks[p][kr][cb + 0] = rk0;
    *(uint4*)&Ks[p][kr][cb + 8] = rk1;
    *(uint4*)&Ks[p][kr][cb + 16] = rk2;
    *(uint4*)&Ks[p][kr][cb + 24] = rk3;
    *(uint4*)&Vts[p][tt][0 ^ xs] = rv0;
    *(uint4*)&Vts[p][tt][8 ^ xs] = rv1;
    *(uint4*)&Vts[p][tt][16 ^ xs] = rv2;
    *(uint4*)&Vts[p][tt][24 ^ xs] = rv3;
    __syncthreads();  // tile ready

    if (kt + 1 < nkt) {  // prefetch next tile under compute
      const ushortT* kp = kbase + (size_t)(kt + 1) * 32 * DH;
      const ushortT* vp = vbase + (kt + 1) * 32;
      rk0 = *(const uint4*)(kp + 0);  rk1 = *(const uint4*)(kp + 8);
      rk2 = *(const uint4*)(kp + 16); rk3 = *(const uint4*)(kp + 24);
      rv0 = *(const uint4*)(vp + 0);  rv1 = *(const uint4*)(vp + 8);
      rv2 = *(const uint4*)(vp + 16); rv3 = *(const uint4*)(vp + 24);
    }

    // QK^T
    f32x4 sc[2];
#pragma unroll
    for (int ct = 0; ct < 2; ct++)
#pragma unroll
      for (int j = 0; j < 4; j++) sc[ct][j] = 0.f;
#pragma unroll
    for (int ct = 0; ct < 2; ct++)
#pragma unroll
      for (int ks = 0; ks < 4; ks++) {
        short8 kfh = *(const short8*)&Ks[0][ct * 16 + fr][ks * 32 + fq * 8];
        short8 kfl = *(const short8*)&Ks[1][ct * 16 + fr][ks * 32 + fq * 8];
        sc[ct] = __builtin_amdgcn_mfma_f32_16x16x32_bf16(qfh[ks], kfh, sc[ct], 0, 0, 0);
        sc[ct] = __builtin_amdgcn_mfma_f32_16x16x32_bf16(qfh[ks], kfl, sc[ct], 0, 0, 0);
        sc[ct] = __builtin_amdgcn_mfma_f32_16x16x32_bf16(qfl[ks], kfh, sc[ct], 0, 0, 0);
      }

    // online softmax (base-2)
    float alpha[4];
#pragma unroll
    for (int j = 0; j < 4; j++) {
      int qg = q0 + w * 16 + fq * 4 + j;
      float s0 = (kt * 32 + fr <= qg) ? sc[0][j] : -INFINITY;
      float s1 = (kt * 32 + 16 + fr <= qg) ? sc[1][j] : -INFINITY;
      float mx = fmaxf(s0, s1);
      mx = fmaxf(mx, __shfl_xor(mx, 1));
      mx = fmaxf(mx, __shfl_xor(mx, 2));
      mx = fmaxf(mx, __shfl_xor(mx, 4));
      mx = fmaxf(mx, __shfl_xor(mx, 8));
      float mn = fmaxf(m[j], mx);
      float al = exp2f(m[j] - mn);
      float p0 = exp2f(s0 - mn), p1 = exp2f(s1 - mn);
      float rs = p0 + p1;
      rs += __shfl_xor(rs, 1);
      rs += __shfl_xor(rs, 2);
      rs += __shfl_xor(rs, 4);
      rs += __shfl_xor(rs, 8);
      l[j] = l[j] * al + rs;
      m[j] = mn;
      alpha[j] = al;
      Ps[w][fq * 4 + j][fr] = f2bf(p0);
      Ps[w][fq * 4 + j][16 + fr] = f2bf(p1);
    }
#pragma unroll
    for (int nt = 0; nt < 8; nt++) {
      oacc[nt][0] *= alpha[0];
      oacc[nt][1] *= alpha[1];
      oacc[nt][2] *= alpha[2];
      oacc[nt][3] *= alpha[3];
    }

    // PV
    short8 pah = *(const short8*)&Ps[w][fr][fq * 8];
#pragma unroll
    for (int nt = 0; nt < 8; nt++) {
      int vr = nt * 16 + fr;
      int vc = (fq * 8) ^ ((fr & 3) << 3);
      short8 vfh = *(const short8*)&Vts[0][vr][vc];
      short8 vfl = *(const short8*)&Vts[1][vr][vc];
      oacc[nt] = __builtin_amdgcn_mfma_f32_16x16x32_bf16(pah, vfh, oacc[nt], 0, 0, 0);
      oacc[nt] = __builtin_amdgcn_mfma_f32_16x16x32_bf16(pah, vfl, oacc[nt], 0, 0, 0);
    }
  }

  float inv[4];
#pragma unroll
  for (int j = 0; j < 4; j++) inv[j] = 1.f / l[j];
  float* ob = O + ((size_t)bh * SEQ + q0 + w * 16 + fq * 4) * DH + fr;
#pragma unroll
  for (int nt = 0; nt < 8; nt++)
#pragma unroll
    for (int j = 0; j < 4; j++)
      ob[(size_t)j * DH + nt * 16] = oacc[nt][j] * inv[j];
}

// ---------------------------------------------------------------------------
// Scatter O (b,h,l2,d2) -> (b,l,D) planes
// ---------------------------------------------------------------------------
__global__ __launch_bounds__(256) void scatter_o_planes(
    const float* __restrict__ O, ushortT* __restrict__ Sh,
    ushortT* __restrict__ Sl) {
  size_t i4 = (size_t)blockIdx.x * 256 + threadIdx.x;
  size_t f = i4 * 4;
  int b = (int)(f >> 22);
  int rem = (int)(f & 4194303);
  int l = rem >> 11, d = rem & 2047;
  int c = l * 16 + (d >> 7);
  int h = c >> 11, l2 = c & 2047, d2 = d & 127;
  float4 v = *(const float4*)&O[(((size_t)b * NH + h) * SEQ + l2) * DH + d2];
  float vv[4] = {v.x, v.y, v.z, v.w};
  us4 hv, lv;
#pragma unroll
  for (int i = 0; i < 4; i++) {
    ushortT h16 = f2bf(vv[i]);
    hv[i] = h16;
    lv[i] = f2bf(vv[i] - bf2f(h16));
  }
  *(us4*)&Sh[f] = hv;
  *(us4*)&Sl[f] = lv;
}

// ---------------------------------------------------------------------------
extern "C" void kernel_launch(void* const* d_in, const int* in_sizes, int n_in,
                              void* d_out, int out_size, void* d_ws,
                              size_t ws_size, hipStream_t stream) {
  // Workspace: 56,885,248 floats = 227,540,992 bytes (== R5-proven guard).
  if (ws_size < 56885248ull * 4ull) return;

  const float* x  = (const float*)d_in[0];
  const float* g1 = (const float*)d_in[1];
  const float* wq = (const float*)d_in[2];
  const float* bq = (const float*)d_in[3];
  const float* wk = (const float*)d_in[4];
  const float* bk = (const float*)d_in[5];
  const float* wv = (const float*)d_in[6];
  const float* bv = (const float*)d_in[7];
  const float* wo = (const float*)d_in[8];
  const float* bo = (const float*)d_in[9];
  const float* g2 = (const float*)d_in[10];
  const float* w1 = (const float*)d_in[11];
  const float* b1 = (const float*)d_in[12];
  const float* wg = (const float*)d_in[13];
  const float* bg = (const float*)d_in[14];
  const float* w2 = (const float*)d_in[15];
  const float* b2 = (const float*)d_in[16];
  float* out = (float*)d_out;
  float* ws = (float*)d_ws;

  // regions (float offsets), aliased by lifetime:
  // WT1 [0, 11534336): qkv planes -> wo planes -> w1 planes -> w2 planes
  // WT2 [11534336, 23068672): biasqkv -> O (attn out) -> wg planes
  // H   [23068672, 31457280): h planes -> h2 planes
  // qkv [31457280, 44040192): fused qkv fp32 -> (m-planes part)
  // Qp  [44040192, 52428800): Q planes -> scatter planes -> (m-planes part)
  // Kp  [52428800, 54525952): K planes -> (m-planes part)
  // Vp  [54525952, 56623104): V planes
  // tab [56623104, 56885248)
  ushortT* WT1u = (ushortT*)(ws + 0);
  float*   WT2f = ws + 11534336;
  ushortT* WT2u = (ushortT*)WT2f;
  ushortT* Hh   = (ushortT*)(ws + 23068672);
  ushortT* Hl   = Hh + 8388608;
  float*   qkv  = ws + 31457280;
  ushortT* Qh   = (ushortT*)(ws + 44040192);
  ushortT* Ql   = Qh + 8388608;
  ushortT* Kh   = (ushortT*)(ws + 52428800);
  ushortT* Kl   = Kh + 2097152;
  ushortT* Vth  = (ushortT*)(ws + 54525952);
  ushortT* Vtl  = Vth + 2097152;
  float*   tab  = ws + 56623104;
  float*   biasqkv = WT2f;             // used only during qkv-gemm
  float*   O    = WT2f;                // attn out (after biasqkv dead)
  ushortT* Sh   = Qh;                  // scatter planes reuse Q planes
  ushortT* Sl   = Sh + 8388608;
  ushortT* Mh   = (ushortT*)qkv;       // m planes span qkv+Qp+Kp (23.07M f)
  ushortT* Ml   = Mh + 23068672;

  rope_table_kernel<<<(SEQ * 64 + 255) / 256, 256, 0, stream>>>(tab);
  bias_cat<<<(QKVD + 255) / 256, 256, 0, stream>>>(bq, bk, bv, biasqkv);
  rmsnorm_planes<<<MROWS, 256, 0, stream>>>(x, g1, Hh, Hl);

  // fused QKV: combined weight planes [3072][2048]
  split_wt<<<dim3(DM / 64, DM / 64), 256, 0, stream>>>(
      wq, WT1u, WT1u + (size_t)QKVD * DM, DM, DM);
  split_wt<<<dim3(KVD / 64, DM / 64), 256, 0, stream>>>(
      wk, WT1u + (size_t)DM * DM, WT1u + (size_t)QKVD * DM + (size_t)DM * DM,
      DM, KVD);
  split_wt<<<dim3(KVD / 64, DM / 64), 256, 0, stream>>>(
      wv, WT1u + (size_t)(DM + KVD) * DM,
      WT1u + (size_t)QKVD * DM + (size_t)(DM + KVD) * DM, DM, KVD);
  gemm_pl<0><<<dim3(QKVD / 128, MROWS / 128), 256, 0, stream>>>(
      Hh, Hl, WT1u, WT1u + (size_t)QKVD * DM, biasqkv, nullptr, qkv, MROWS,
      QKVD, DM);

  gather_rope_q_bf<<<(BATCH * NH * SEQ) / 4, 256, 0, stream>>>(qkv, tab, Qh, Ql);
  gather_k_bf<<<(BATCH * NG * SEQ) / 4, 256, 0, stream>>>(qkv, tab, Kh, Kl);
  gather_vt_bf<<<dim3(SEQ / 64, DH / 32, BATCH * NG), 256, 0, stream>>>(
      qkv, Vth, Vtl);

  attn_mfma<<<dim3(SEQ / 64, BATCH * NH), 256, 0, stream>>>(Qh, Ql, Kh, Kl,
                                                            Vth, Vtl, O);
  scatter_o_planes<<<(MROWS * DM / 4) / 256, 256, 0, stream>>>(O, Sh, Sl);

  // x2 = x + attn @ wo + bo   (x2 lives in d_out)
  split_wt<<<dim3(DM / 64, DM / 64), 256, 0, stream>>>(
      wo, WT1u, WT1u + (size_t)DM * DM, DM, DM);
  gemm_pl<1><<<dim3(DM / 128, MROWS / 128), 256, 0, stream>>>(
      Sh, Sl, WT1u, WT1u + (size_t)DM * DM, bo, x, out, MROWS, DM, DM);

  // h2 planes
  rmsnorm_planes<<<MROWS, 256, 0, stream>>>(out, g2, Hh, Hl);

  // m = silu(h2@w1+b1) * (h2@wg+bg)  (planes out; dual-B)
  split_wt<<<dim3(HDIM / 64, DM / 64), 256, 0, stream>>>(
      w1, WT1u, WT1u + (size_t)HDIM * DM, DM, HDIM);
  split_wt<<<dim3(HDIM / 64, DM / 64), 256, 0, stream>>>(
      wg, WT2u, WT2u + (size_t)HDIM * DM, DM, HDIM);
  gemm_dual<<<dim3(HDIM / 128, MROWS / 128), 512, 0, stream>>>(
      Hh, Hl, WT1u, WT1u + (size_t)HDIM * DM, WT2u, WT2u + (size_t)HDIM * DM,
      b1, bg, Mh, Ml, MROWS, HDIM, DM);

  // out = x2 + m @ w2 + b2   (in-place aux read; store depends on load)
  split_wt<<<dim3(DM / 64, HDIM / 64), 256, 0, stream>>>(
      w2, WT1u, WT1u + (size_t)DM * HDIM, HDIM, DM);
  gemm_pl<1><<<dim3(DM / 128, MROWS / 128), 256, 0, stream>>>(
      Mh, Ml, WT1u, WT1u + (size_t)DM * HDIM, b2, out, out, MROWS, DM, HDIM);
}